// Round 13
// baseline (1225.409 us; speedup 1.0000x reference)
//
#include <hip/hip_runtime.h>
#include <hip/hip_bf16.h>
#include <cstdint>

#define B_ 16
#define N_ 2048
#define KNN_K 20
#define EPS_ 1e-5f
#define SLOPE_ 0.2f
#define IMS 4.8828125e-4f   // 1/2048

typedef __attribute__((ext_vector_type(4))) float f32x4;
typedef __attribute__((ext_vector_type(8))) short bf16x8;
typedef __attribute__((ext_vector_type(8))) _Float16 f16x8;

typedef const __attribute__((address_space(1))) void* as1cv;
typedef __attribute__((address_space(3))) void* as3v;

static __device__ __forceinline__ float lrelu(float v){ return v > 0.f ? v : SLOPE_*v; }

static __device__ __forceinline__ unsigned encf(float f){
  unsigned b = __float_as_uint(f);
  return (b & 0x80000000u) ? ~b : (b | 0x80000000u);
}
static __device__ __forceinline__ float decf(unsigned u){
  unsigned b = (u & 0x80000000u) ? (u ^ 0x80000000u) : ~u;
  return __uint_as_float(b);
}
static __device__ __forceinline__ short bfbits(float v){
  __hip_bfloat16 h = __float2bfloat16(v);
  return *reinterpret_cast<short*>(&h);
}
static __device__ __forceinline__ short h16(float v){
  _Float16 h = (_Float16)v;
  return *reinterpret_cast<short*>(&h);
}
static __device__ __forceinline__ float h2f(short s){
  _Float16 h = *reinterpret_cast<_Float16*>(&s);
  return (float)h;
}

// ---------------- convert: f -> 2 fp16 planes (h, (v-h)*2048) + xx (fp32) ----------------
template<int C, int CP>
__global__ __launch_bounds__(256) void convert_kernel(const float* __restrict__ f, int lda,
                                                      short* __restrict__ fbf, size_t plane,
                                                      float* __restrict__ xx){
  int wid  = (blockIdx.x * 256 + threadIdx.x) >> 6;   // one wave per row
  int lane = threadIdx.x & 63;
  if (wid >= B_*N_) return;
  const float* p = f + (size_t)wid*lda;
  float s = 0.f;
  for (int c = lane; c < CP; c += 64){
    float v = (c < C) ? p[c] : 0.f;
    short h = h16(v);
    short m = h16((v - h2f(h)) * 2048.f);
    size_t o = (size_t)wid*CP + c;
    fbf[o] = h;
    fbf[plane + o] = m;
    s += v*v;
  }
  #pragma unroll
  for (int off=32; off; off>>=1) s += __shfl_down(s, off);
  if (lane==0) xx[wid] = s;
}

// ---------------- fused MFMA distance (fp16 2-plane) + wave-coop top-20, m-split ----------------
// Staging via global_load_lds (async, no VGPR round-trip): linear LDS [64][CP] per plane,
// source pre-swizzled byte^=(row&SMASK)<<4, reads apply the same swizzle (rule #21).
// Per tile: MFMA -> dtile -> bar -> issue glds(t+1) -> selection (hides load latency) -> bar.
template<int CP>
__global__ __launch_bounds__(256) void knn_mfma(const short* __restrict__ fbf, size_t plane,
                                                const float* __restrict__ xx,
                                                float* __restrict__ pval, int* __restrict__ pidx){
  constexpr int KC = CP/32;
  constexpr int ROWB = CP*2;           // bytes per row
  constexpr int LPR = ROWB/16;         // lanes per row (4/8/16)
  constexpr int RPI = 64/LPR;          // rows per glds instr (16/8/4)
  constexpr int NI  = 64/RPI;          // instrs per plane per tile (4/8/16)
  constexpr int SMASK = (ROWB/16 >= 8) ? 7 : (ROWB/16 - 1);
  __shared__ __align__(16) short fmb[2*64*CP];
  __shared__ float dtile[64*65];
  __shared__ float xn_s[64], xm_s[64];

  int b   = blockIdx.x >> 6;
  int rem = blockIdx.x & 63;
  int n0  = (rem >> 1) << 6;
  int mh  = rem & 1;
  int mbase = mh << 10;
  int tid = threadIdx.x;
  int w    = tid >> 6;
  int lane = tid & 63;
  int fr = lane & 15, hi = lane >> 4;
  int r_loc = lane >> 2, csub = lane & 3;
  int gb = lane & 60;
  int myrow = w*16 + r_loc;
  size_t browoff = (size_t)b * N_;

  // fn A-fragments -- m-tile invariant, registers (row-major source, no swizzle)
  f16x8 aH[KC], aM[KC];
  {
    size_t arow = (browoff + n0 + w*16 + fr) * (size_t)CP;
    #pragma unroll
    for (int kc=0; kc<KC; ++kc){
      aH[kc] = *(const f16x8*)&fbf[arow + kc*32 + hi*8];
      aM[kc] = *(const f16x8*)&fbf[plane + arow + kc*32 + hi*8];
    }
  }

  float sv[5]; int si[5];
  #pragma unroll
  for (int j=0;j<5;++j){ sv[j] = -1e30f; si[j] = 0x7FFFFFFF; }

  // per-lane pre-swizzled source byte offsets (within an instr-group of RPI rows)
  unsigned lofs[2];
  {
    int lsub = tid & 63;   // staging uses whole block; each wave issues for its own tid? -> use tid
  }
  // staging: 256 threads, but glds is per-wave (64 lanes). Wave w handles instrs j where j%4==w.
  unsigned lo0, lo1;
  {
    int rg = lane / LPR;               // row within instr-group
    int ib = (lane % LPR) * 16;        // in-row byte
    lo0 = (unsigned)(rg*ROWB + (ib ^ ((rg & SMASK) << 4)));
    int rg1 = rg + ((RPI == 4) ? 4 : 0);
    lo1 = (unsigned)(rg*ROWB + (ib ^ ((rg1 & SMASK) << 4)));
  }

  const char* fbfB = (const char*)fbf;
  size_t planeB = plane * 2;

  auto GLDS = [&](int mt){
    size_t baseB = (browoff + mbase + ((size_t)mt << 6)) * (size_t)ROWB;
    const char* sH = fbfB + baseB;
    #pragma unroll
    for (int j = w; j < NI; j += 4){   // wave w issues its share
      unsigned lo = ((RPI == 4) && (j & 1)) ? lo1 : lo0;
      const char* srcH = sH + (size_t)j*RPI*ROWB + lo;
      __builtin_amdgcn_global_load_lds((as1cv)srcH, (as3v)&fmb[j*RPI*CP], 16, 0, 0);
      __builtin_amdgcn_global_load_lds((as1cv)(srcH + planeB), (as3v)&fmb[64*CP + j*RPI*CP], 16, 0, 0);
    }
  };

  // prologue
  GLDS(0);
  float xmreg = 0.f;
  if (tid < 64){
    xn_s[tid] = xx[browoff + n0 + tid];
    xm_s[tid] = xx[browoff + mbase + tid];
  }
  __syncthreads();   // drains glds + xn/xm ready

  for (int mt = 0; mt < 16; ++mt){
    int m0 = mbase + (mt << 6);

    f32x4 accH[4], accM[4];
    #pragma unroll
    for (int ct=0; ct<4; ++ct){ accH[ct] = (f32x4){0.f,0.f,0.f,0.f}; accM[ct] = accH[ct]; }
    #pragma unroll
    for (int kc = 0; kc < KC; ++kc){
      #pragma unroll
      for (int ct=0; ct<4; ++ct){
        int boff = (ct*16 + fr)*CP + ((((kc*64 + hi*16) ^ ((fr & SMASK) << 4))) >> 1);
        f16x8 bh = *(const f16x8*)&fmb[boff];
        f16x8 bm = *(const f16x8*)&fmb[64*CP + boff];
        accH[ct] = __builtin_amdgcn_mfma_f32_16x16x32_f16(aH[kc], bh, accH[ct], 0,0,0);
        accM[ct] = __builtin_amdgcn_mfma_f32_16x16x32_f16(aM[kc], bh, accM[ct], 0,0,0);
        accM[ct] = __builtin_amdgcn_mfma_f32_16x16x32_f16(aH[kc], bm, accM[ct], 0,0,0);
      }
    }
    // dtile: D row=(lane>>4)*4+reg, col=lane&15 per 16x16 tile (own-wave rows)
    #pragma unroll
    for (int reg=0; reg<4; ++reg){
      int nl = w*16 + hi*4 + reg;
      float xn = xn_s[nl];
      #pragma unroll
      for (int ct=0; ct<4; ++ct)
        dtile[nl*65 + ct*16 + fr] = 2.f*(accH[ct][reg] + IMS*accM[ct][reg]) - xn - xm_s[ct*16 + fr];
    }
    __syncthreads();   // all fmb reads + xm_s reads done -> safe to overwrite

    if (mt + 1 < 16){
      GLDS(mt + 1);                                   // async, hidden under selection
      if (tid < 64) xmreg = xx[browoff + mbase + ((mt+1)<<6) + tid];
    }

    // ---- wave-cooperative selection (r8-proven, bit-exact) ----
    int base = myrow*65 + csub*16;
    float thr = __shfl(sv[4], lane | 3);
    unsigned qm = 0u;
    #pragma unroll
    for (int jj=0; jj<16; ++jj){
      float v = dtile[base + jj];
      qm |= (v > thr) ? (1u << jj) : 0u;
    }
    unsigned long long bal = __ballot(qm != 0u);
    while (bal){
      unsigned nib = (unsigned)((bal >> gb) & 0xFull);
      int leader = nib ? (gb + (int)__builtin_ctz(nib)) : 64;
      int bbit = (int)__builtin_ctz(qm | 0x10000u);
      float mv = dtile[base + (bbit & 15)];
      int mid = m0 + (csub << 4) + bbit;
      float cv = __shfl(mv, leader);
      int   cid = __shfl(mid, leader);
      qm = (lane == leader) ? (qm & (qm - 1u)) : qm;
      int cnt = 0;
      #pragma unroll
      for (int j=0;j<5;++j) cnt += (sv[j] >= cv) ? 1 : 0;
      cnt += __shfl_xor(cnt, 1);
      cnt += __shfl_xor(cnt, 2);
      int pos = nib ? cnt : 20;
      float pv = __shfl_up(sv[4], 1);
      int   pi = __shfl_up(si[4], 1);
      #pragma unroll
      for (int j=0;j<5;++j){
        int g = csub*5 + j;
        float ns = (g < pos) ? sv[j] : ((g == pos) ? cv : pv);
        int   ni = (g < pos) ? si[j] : ((g == pos) ? cid : pi);
        pv = sv[j]; pi = si[j];
        sv[j] = ns; si[j] = ni;
      }
      bal = __ballot(qm != 0u);
    }

    if (mt + 1 < 16){
      if (tid < 64) xm_s[tid] = xmreg;
      __syncthreads();   // glds(t+1) drained (compiler vmcnt0) + xm_s ready
    }
  }

  size_t orow = browoff + n0 + myrow;
  float* pvo = pval + (orow*2 + mh)*KNN_K + csub*5;
  int*   pio = pidx + (orow*2 + mh)*KNN_K + csub*5;
  #pragma unroll
  for (int j=0;j<5;++j){ pvo[j] = sv[j]; pio[j] = si[j]; }
}

// ---------------- merge two sorted-20 partial lists per row ----------------
__global__ __launch_bounds__(256) void knn_merge(const float* __restrict__ pval,
                                                 const int* __restrict__ pidx,
                                                 int* __restrict__ idxout){
  int r = blockIdx.x*256 + threadIdx.x;
  if (r >= B_*N_) return;
  const float* va = pval + (size_t)r*2*KNN_K;
  const float* vb = va + KNN_K;
  const int*   ia = pidx + (size_t)r*2*KNN_K;
  const int*   ib = ia + KNN_K;
  int i=0, j=0;
  #pragma unroll
  for (int t=0;t<KNN_K;++t){
    float a = va[i], bq = vb[j];
    bool ta = (a >= bq);   // tie -> half 0 (lower ids)
    idxout[(size_t)r*KNN_K + t] = ta ? ia[i] : ib[j];
    i += ta ? 1 : 0; j += ta ? 0 : 1;
  }
}

// ---------------- combined P+Q GEMM (fp16 2-plane): A staged once, wq = wB - wA inline ----------------
template<int CP>
__global__ __launch_bounds__(256) void gemm_pq2(const short* __restrict__ fbf, size_t plane,
                                                const float* __restrict__ Wsrc, int Cin,
                                                float* __restrict__ P, float* __restrict__ Qo, int O){
  constexpr int BK = (CP < 64) ? CP : 64;
  constexpr int SP = BK + 8;
  __shared__ short Ah[64*SP];
  __shared__ short Am[64*SP];
  __shared__ short WAh[64*SP];
  __shared__ short WAm[64*SP];
  __shared__ short WQh[64*SP];
  __shared__ short WQm[64*SP];
  int obl = O >> 6;
  int bo = ((int)blockIdx.x % obl) << 6;
  int bm = ((int)blockIdx.x / obl) << 6;
  int tid = threadIdx.x;
  int w = tid >> 6, lane = tid & 63;
  int fr = lane & 15, hi = lane >> 4;
  f32x4 aPH[4], aPM[4], aQH[4], aQM[4];
  #pragma unroll
  for (int ct=0; ct<4; ++ct){
    aPH[ct] = (f32x4){0.f,0.f,0.f,0.f};
    aPM[ct] = aPH[ct]; aQH[ct] = aPH[ct]; aQM[ct] = aPH[ct];
  }

  for (int k0=0; k0<CP; k0+=BK){
    __syncthreads();
    for (int i=tid; i < 64*(BK/8); i += 256){
      int r = i/(BK/8), cq = i%(BK/8);
      size_t src = ((size_t)bm + r)*CP + k0 + cq*8;
      *(f16x8*)&Ah[r*SP + cq*8] = *(const f16x8*)&fbf[src];
      *(f16x8*)&Am[r*SP + cq*8] = *(const f16x8*)&fbf[plane + src];
    }
    for (int i=tid; i < 64*(BK/8); i += 256){
      int r = i/(BK/8), cq = i%(BK/8);
      f16x8 vah, vam, vqh, vqm;
      #pragma unroll
      for (int e=0;e<8;++e){
        int c = k0 + cq*8 + e;
        float wa = 0.f, wqv = 0.f;
        if (c < Cin){
          wa  = Wsrc[(size_t)(bo + r)*2*Cin + c];
          wqv = Wsrc[(size_t)(bo + r)*2*Cin + Cin + c] - wa;
        }
        _Float16 ha = (_Float16)wa;
        vah[e] = ha;
        vam[e] = (_Float16)((wa - (float)ha) * 2048.f);
        _Float16 hq = (_Float16)wqv;
        vqh[e] = hq;
        vqm[e] = (_Float16)((wqv - (float)hq) * 2048.f);
      }
      *(f16x8*)&WAh[r*SP + cq*8] = vah;
      *(f16x8*)&WAm[r*SP + cq*8] = vam;
      *(f16x8*)&WQh[r*SP + cq*8] = vqh;
      *(f16x8*)&WQm[r*SP + cq*8] = vqm;
    }
    __syncthreads();
    #pragma unroll
    for (int kc=0; kc<BK/32; ++kc){
      f16x8 ah = *(const f16x8*)&Ah[(w*16 + fr)*SP + kc*32 + hi*8];
      f16x8 am = *(const f16x8*)&Am[(w*16 + fr)*SP + kc*32 + hi*8];
      #pragma unroll
      for (int ct=0; ct<4; ++ct){
        int boff = (ct*16 + fr)*SP + kc*32 + hi*8;
        f16x8 bh = *(const f16x8*)&WAh[boff];
        f16x8 bm = *(const f16x8*)&WAm[boff];
        f16x8 qh = *(const f16x8*)&WQh[boff];
        f16x8 qm = *(const f16x8*)&WQm[boff];
        aPH[ct] = __builtin_amdgcn_mfma_f32_16x16x32_f16(ah, bh, aPH[ct], 0,0,0);
        aPM[ct] = __builtin_amdgcn_mfma_f32_16x16x32_f16(am, bh, aPM[ct], 0,0,0);
        aPM[ct] = __builtin_amdgcn_mfma_f32_16x16x32_f16(ah, bm, aPM[ct], 0,0,0);
        aQH[ct] = __builtin_amdgcn_mfma_f32_16x16x32_f16(ah, qh, aQH[ct], 0,0,0);
        aQM[ct] = __builtin_amdgcn_mfma_f32_16x16x32_f16(am, qh, aQM[ct], 0,0,0);
        aQM[ct] = __builtin_amdgcn_mfma_f32_16x16x32_f16(ah, qm, aQM[ct], 0,0,0);
      }
    }
  }
  #pragma unroll
  for (int ct=0; ct<4; ++ct)
    #pragma unroll
    for (int reg=0; reg<4; ++reg){
      int row = bm + w*16 + hi*4 + reg;
      size_t o = (size_t)row*O + bo + ct*16 + fr;
      P[o]  = aPH[ct][reg] + IMS*aPM[ct][reg];
      Qo[o] = aQH[ct][reg] + IMS*aQM[ct][reg];
    }
}

// ---------------- conv5 GEMM (bf16 staged) with fused BN stats + signed max epilogue ----------------
__global__ __launch_bounds__(256) void gemm_bf16_stats(const float* __restrict__ A,
                                                       const float* __restrict__ Wt,
                                                       const float* __restrict__ g5,
                                                       float* __restrict__ sums,
                                                       float* __restrict__ sumsq,
                                                       unsigned* __restrict__ maxenc){
  __shared__ short As[128*72];
  __shared__ short Bs[64*72];
  __shared__ float s1[64], s2[64];
  int bm = (int)(blockIdx.x >> 3) << 7;
  int bo = (int)(blockIdx.x & 7) << 6;
  int tid = threadIdx.x;
  int w = tid >> 6, lane = tid & 63;
  int fr = lane & 15, hi = lane >> 4;
  f32x4 acc[2][4];
  #pragma unroll
  for (int g=0; g<2; ++g)
    #pragma unroll
    for (int ct=0; ct<4; ++ct) acc[g][ct] = (f32x4){0.f,0.f,0.f,0.f};

  for (int k0=0; k0<512; k0+=64){
    __syncthreads();
    #pragma unroll 2
    for (int i = tid; i < 1024; i += 256){
      int r = i >> 3, cq = i & 7;
      const float* src = &A[(size_t)(bm + r)*512 + k0 + cq*8];
      bf16x8 v;
      #pragma unroll
      for (int e=0;e<8;++e) v[e] = bfbits(src[e]);
      *(bf16x8*)&As[r*72 + cq*8] = v;
    }
    #pragma unroll 2
    for (int i = tid; i < 512; i += 256){
      int r = i >> 3, cq = i & 7;
      const float* src = &Wt[(size_t)(bo + r)*512 + k0 + cq*8];
      bf16x8 v;
      #pragma unroll
      for (int e=0;e<8;++e) v[e] = bfbits(src[e]);
      *(bf16x8*)&Bs[r*72 + cq*8] = v;
    }
    __syncthreads();
    #pragma unroll
    for (int kc=0; kc<2; ++kc){
      bf16x8 a0 = *(const bf16x8*)&As[(w*32 +      fr)*72 + kc*32 + hi*8];
      bf16x8 a1 = *(const bf16x8*)&As[(w*32 + 16 + fr)*72 + kc*32 + hi*8];
      #pragma unroll
      for (int ct=0; ct<4; ++ct){
        bf16x8 bb = *(const bf16x8*)&Bs[(ct*16 + fr)*72 + kc*32 + hi*8];
        acc[0][ct] = __builtin_amdgcn_mfma_f32_16x16x32_bf16(a0, bb, acc[0][ct], 0,0,0);
        acc[1][ct] = __builtin_amdgcn_mfma_f32_16x16x32_bf16(a1, bb, acc[1][ct], 0,0,0);
      }
    }
  }

  __syncthreads();
  if (tid < 64){ s1[tid] = 0.f; s2[tid] = 0.f; }
  __syncthreads();
  int bidx = bm >> 11;
  #pragma unroll
  for (int ct=0; ct<4; ++ct){
    int o = bo + ct*16 + fr;
    float ga = g5[o];
    float s = 0.f, ss = 0.f, mx = -1e30f;
    #pragma unroll
    for (int g=0; g<2; ++g)
      #pragma unroll
      for (int reg=0; reg<4; ++reg){
        float v = acc[g][ct][reg];
        s += v; ss += v*v;
        float sel = ga >= 0.f ? v : -v;
        mx = fmaxf(mx, sel);
      }
    s  += __shfl_xor(s, 16);  s  += __shfl_xor(s, 32);
    ss += __shfl_xor(ss, 16); ss += __shfl_xor(ss, 32);
    mx = fmaxf(mx, __shfl_xor(mx, 16)); mx = fmaxf(mx, __shfl_xor(mx, 32));
    if (hi == 0){
      atomicAdd(&s1[ct*16 + fr], s);
      atomicAdd(&s2[ct*16 + fr], ss);
      atomicMax(&maxenc[bidx*512 + o], encf(mx));
    }
  }
  __syncthreads();
  if (tid < 64){
    atomicAdd(&sums[bo + tid],  s1[tid]);
    atomicAdd(&sumsq[bo + tid], s2[tid]);
  }
}

__global__ void zero_f_kernel(float* p, int n){
  int i = blockIdx.x*blockDim.x + threadIdx.x;
  if (i < n) p[i] = 0.f;
}
__global__ void zero_u_kernel(unsigned* p, int n){
  int i = blockIdx.x*blockDim.x + threadIdx.x;
  if (i < n) p[i] = 0u;
}

// ---------------- edge aggregation: gather P, stats + selected extreme ----------------
__global__ __launch_bounds__(256) void edge_agg(const float* __restrict__ P, const float* __restrict__ Q,
      const int* __restrict__ idx, const float* __restrict__ gamma,
      float* __restrict__ S, float* __restrict__ sums, float* __restrict__ sumsq, int O){
  const int ROWS = 64;
  int rpi = 256 / O;
  int iters = ROWS / rpi;
  int row0 = blockIdx.x * ROWS;
  int tid = threadIdx.x;
  int o  = tid % O;
  int rl = tid / O;
  int b  = row0 / N_;
  __shared__ int sidx[4][KNN_K];
  __shared__ float s1[256], s2[256];
  float g = gamma[o];
  float csum=0.f, csumsq=0.f;
  for (int it=0; it<iters; ++it){
    __syncthreads();
    if (tid < KNN_K*rpi) sidx[tid/KNN_K][tid%KNN_K] = idx[(size_t)(row0 + it*rpi)*KNN_K + tid];
    __syncthreads();
    int row = row0 + it*rpi + rl;
    float q = Q[(size_t)row*O + o];
    float mx=-1e30f, mn=1e30f, s=0.f, ss=0.f;
    #pragma unroll
    for (int k=0;k<KNN_K;++k){
      int m = sidx[rl][k];
      float p = P[((size_t)b*N_ + m)*O + o];
      mx = fmaxf(mx,p); mn = fminf(mn,p);
      float y = p + q; s += y; ss += y*y;
    }
    csum += s; csumsq += ss;
    S[(size_t)row*O + o] = (g >= 0.f ? mx : mn) + q;
  }
  s1[tid]=0.f; s2[tid]=0.f;
  __syncthreads();
  atomicAdd(&s1[o], csum); atomicAdd(&s2[o], csumsq);
  __syncthreads();
  if (tid < O){ atomicAdd(&sums[tid], s1[tid]); atomicAdd(&sumsq[tid], s2[tid]); }
}

// ---------------- BN finalize ----------------
__global__ void bn_finalize(const float* __restrict__ sums, const float* __restrict__ sumsq,
                            const float* __restrict__ gamma, const float* __restrict__ beta,
                            float invM, float* __restrict__ scale, float* __restrict__ shift, int O){
  int o = blockIdx.x*blockDim.x + threadIdx.x;
  if (o >= O) return;
  float mu = sums[o]*invM;
  float var = sumsq[o]*invM - mu*mu;
  float rs = rsqrtf(var + EPS_);
  float sc = gamma[o]*rs;
  scale[o] = sc; shift[o] = beta[o] - mu*sc;
}

// ---------------- apply affine+lrelu, write into cat ----------------
__global__ void apply_write(const float* __restrict__ S, const float* __restrict__ scale,
                            const float* __restrict__ shift, float* __restrict__ cat, int off, int O){
  int i = blockIdx.x*blockDim.x + threadIdx.x;
  if (i >= B_*N_*O) return;
  int row = i / O, o = i - row*O;
  float v = S[i]*scale[o] + shift[o];
  cat[(size_t)row*512 + off + o] = lrelu(v);
}

// ---------------- pool ----------------
__global__ void pool_kernel(const unsigned* __restrict__ maxenc, const float* __restrict__ scale,
                            const float* __restrict__ shift, const float* __restrict__ g5,
                            float* __restrict__ pooled){
  int i = blockIdx.x*blockDim.x + threadIdx.x;
  if (i >= B_*512) return;
  int o = i & 511;
  float t = decf(maxenc[i]);
  float y = g5[o] >= 0.f ? t : -t;
  pooled[i] = lrelu(y*scale[o] + shift[o]);
}

// ---------------- final projection ----------------
__global__ void final_mm(const float* __restrict__ pooled, const float* __restrict__ we,
                         float* __restrict__ out){
  int i = blockIdx.x*blockDim.x + threadIdx.x;
  if (i >= B_*128) return;
  int b = i >> 7, j = i & 127;
  const float4* pp = (const float4*)(pooled + (size_t)b*512);
  const float4* wp = (const float4*)(we + (size_t)j*512);
  float s = 0.f;
  for (int c=0;c<128;++c){
    float4 a = pp[c], w = wp[c];
    s += a.x*w.x + a.y*w.y + a.z*w.z + a.w*w.w;
  }
  out[i] = s;
}

// ---------------- driver ----------------
struct Ws {
  float* cat; float* P; float* Q; float* S; int* idx; float* xx;
  float* sums; float* sumsq; float* scale; float* shift;
  unsigned* maxenc; float* pooled; short* fbf;
  float* pval; int* pidx;
};

template<int C, int CP>
static void run_layer(const Ws& W, const float* f, int lda, int O,
                      const float* w, const float* g, const float* bt,
                      int off_out, hipStream_t stream){
  const int M = B_*N_;
  size_t plane = (size_t)M*CP;
  convert_kernel<C, CP><<<M/4, 256, 0, stream>>>(f, lda, W.fbf, plane, W.xx);
  knn_mfma<CP><<<B_*(N_/64)*2, 256, 0, stream>>>(W.fbf, plane, W.xx, W.pval, W.pidx);
  knn_merge<<<(M+255)/256, 256, 0, stream>>>(W.pval, W.pidx, W.idx);
  int grid = (M/64)*(O/64);
  gemm_pq2<CP><<<grid, 256, 0, stream>>>(W.fbf, plane, w, C, W.P, W.Q, O);
  zero_f_kernel<<<4, 256, 0, stream>>>(W.sums, 1024);
  edge_agg<<<M/64, 256, 0, stream>>>(W.P, W.Q, W.idx, g, W.S, W.sums, W.sumsq, O);
  bn_finalize<<<(O+255)/256, 256, 0, stream>>>(W.sums, W.sumsq, g, bt,
                                               1.f/((float)M*KNN_K), W.scale, W.shift, O);
  apply_write<<<(M*O+255)/256, 256, 0, stream>>>(W.S, W.scale, W.shift, W.cat, off_out, O);
}

extern "C" void kernel_launch(void* const* d_in, const int* in_sizes, int n_in,
                              void* d_out, int out_size, void* d_ws, size_t ws_size,
                              hipStream_t stream) {
  const float* x  = (const float*)d_in[0];
  const float* w1 = (const float*)d_in[1];
  const float* g1 = (const float*)d_in[2];
  const float* b1 = (const float*)d_in[3];
  const float* w2 = (const float*)d_in[4];
  const float* g2 = (const float*)d_in[5];
  const float* b2 = (const float*)d_in[6];
  const float* w3 = (const float*)d_in[7];
  const float* g3 = (const float*)d_in[8];
  const float* b3 = (const float*)d_in[9];
  const float* w4 = (const float*)d_in[10];
  const float* g4 = (const float*)d_in[11];
  const float* b4 = (const float*)d_in[12];
  const float* w5 = (const float*)d_in[13];
  const float* g5 = (const float*)d_in[14];
  const float* b5 = (const float*)d_in[15];
  const float* we = (const float*)d_in[16];

  char* ws = (char*)d_ws;
  Ws W;
  size_t off = 0;
  W.cat   = (float*)(ws + off); off += (size_t)16*2048*512*4;
  W.P     = (float*)(ws + off); off += (size_t)16*2048*256*4;
  W.Q     = (float*)(ws + off); off += (size_t)16*2048*256*4;
  W.S     = (float*)(ws + off); off += (size_t)16*2048*256*4;
  W.idx   = (int*)  (ws + off); off += (size_t)16*2048*20*4;
  W.xx    = (float*)(ws + off); off += (size_t)16*2048*4;
  W.sums  = (float*)(ws + off); off += 512*4;
  W.sumsq = (float*)(ws + off); off += 512*4;
  W.scale = (float*)(ws + off); off += 512*4;
  W.shift = (float*)(ws + off); off += 512*4;
  W.maxenc= (unsigned*)(ws + off); off += (size_t)16*512*4;
  W.pooled= (float*)(ws + off); off += (size_t)16*512*4;
  W.fbf   = (short*)W.S;            // fbf live [convert, gemm_pq2]; S live [edge_agg, apply_write]
  W.pval  = W.Q;                    // partials live [knn, merge]; Q live [gemm_pq2, edge_agg]
  W.pidx  = (int*)(W.Q + (size_t)2*16*2048*KNN_K);

  const int M = B_*N_;

  run_layer<3,   32>(W, x,           3,   64,  w1, g1, b1, 0,   stream);
  run_layer<64,  64>(W, W.cat,       512, 64,  w2, g2, b2, 64,  stream);
  run_layer<64,  64>(W, W.cat + 64,  512, 128, w3, g3, b3, 128, stream);
  run_layer<128,128>(W, W.cat + 128, 512, 256, w4, g4, b4, 256, stream);

  // conv5 with fused BN-stats + signed-max epilogue (no y5 materialization)
  zero_f_kernel<<<4, 256, 0, stream>>>(W.sums, 1024);
  zero_u_kernel<<<32, 256, 0, stream>>>(W.maxenc, 16*512);
  gemm_bf16_stats<<<(M/128)*8, 256, 0, stream>>>(W.cat, w5, g5, W.sums, W.sumsq, W.maxenc);
  bn_finalize<<<2, 256, 0, stream>>>(W.sums, W.sumsq, g5, b5, 1.f/(float)M, W.scale, W.shift, 512);
  pool_kernel<<<(16*512+255)/256, 256, 0, stream>>>(W.maxenc, W.scale, W.shift, g5, W.pooled);
  final_mm<<<(16*128+255)/256, 256, 0, stream>>>(W.pooled, we, (float*)d_out);
}

// Round 15
// 1190.696 us; speedup vs baseline: 1.0292x; 1.0292x over previous
//
#include <hip/hip_runtime.h>
#include <hip/hip_bf16.h>
#include <cstdint>

#define B_ 16
#define N_ 2048
#define KNN_K 20
#define EPS_ 1e-5f
#define SLOPE_ 0.2f
#define IMS 4.8828125e-4f   // 1/2048

typedef __attribute__((ext_vector_type(4))) float f32x4;
typedef __attribute__((ext_vector_type(8))) short bf16x8;
typedef __attribute__((ext_vector_type(8))) _Float16 f16x8;

static __device__ __forceinline__ float lrelu(float v){ return v > 0.f ? v : SLOPE_*v; }

static __device__ __forceinline__ unsigned encf(float f){
  unsigned b = __float_as_uint(f);
  return (b & 0x80000000u) ? ~b : (b | 0x80000000u);
}
static __device__ __forceinline__ float decf(unsigned u){
  unsigned b = (u & 0x80000000u) ? (u ^ 0x80000000u) : ~u;
  return __uint_as_float(b);
}
static __device__ __forceinline__ short bfbits(float v){
  __hip_bfloat16 h = __float2bfloat16(v);
  return *reinterpret_cast<short*>(&h);
}
static __device__ __forceinline__ short h16(float v){
  _Float16 h = (_Float16)v;
  return *reinterpret_cast<short*>(&h);
}
static __device__ __forceinline__ float h2f(short s){
  _Float16 h = *reinterpret_cast<_Float16*>(&s);
  return (float)h;
}

// ---------------- convert (layer 1 only): x -> 2 fp16 planes + xx ----------------
template<int C, int CP>
__global__ __launch_bounds__(256) void convert_kernel(const float* __restrict__ f, int lda,
                                                      short* __restrict__ fbf, size_t plane,
                                                      float* __restrict__ xx){
  int wid  = (blockIdx.x * 256 + threadIdx.x) >> 6;   // one wave per row
  int lane = threadIdx.x & 63;
  if (wid >= B_*N_) return;
  const float* p = f + (size_t)wid*lda;
  float s = 0.f;
  for (int c = lane; c < CP; c += 64){
    float v = (c < C) ? p[c] : 0.f;
    short h = h16(v);
    short m = h16((v - h2f(h)) * 2048.f);
    size_t o = (size_t)wid*CP + c;
    fbf[o] = h;
    fbf[plane + o] = m;
    s += v*v;
  }
  #pragma unroll
  for (int off=32; off; off>>=1) s += __shfl_down(s, off);
  if (lane==0) xx[wid] = s;
}

// ---------------- fused MFMA distance (fp16 2-plane) + wave-coop top-20, m-split (r8-proven) ----------------
template<int CP>
__global__ __launch_bounds__(256, 2) void knn_mfma(const short* __restrict__ fbf, size_t plane,
                                                const float* __restrict__ xx,
                                                float* __restrict__ pval, int* __restrict__ pidx){
  constexpr int SP = CP + 8;          // shorts per LDS row
  constexpr int CH = CP/8;
  constexpr int KC = CP/32;
  constexpr int PFH = CP/32;          // 16B chunks per thread, H plane only
  constexpr int FMBS = 2*64*SP;       // fmb shorts
  constexpr bool ALIAS = (FMBS*2 >= 64*65*4);
  constexpr unsigned LDSB = ALIAS ? (unsigned)(FMBS*2) : (unsigned)(FMBS*2 + 64*65*4);
  __shared__ __align__(16) char ldsbuf[LDSB];
  short* fmb = (short*)ldsbuf;
  float* dtile = ALIAS ? (float*)ldsbuf : (float*)(ldsbuf + FMBS*2);
  __shared__ float xn_s[64], xm_s[64];

  int b   = blockIdx.x >> 6;
  int rem = blockIdx.x & 63;
  int n0  = (rem >> 1) << 6;
  int mh  = rem & 1;
  int mbase = mh << 10;
  int tid = threadIdx.x;
  int w    = tid >> 6;
  int lane = tid & 63;
  int fr = lane & 15, hi = lane >> 4;
  int r_loc = lane >> 2, csub = lane & 3;
  int gb = lane & 60;
  int myrow = w*16 + r_loc;
  size_t browoff = (size_t)b * N_;

  f16x8 aH[KC], aM[KC];
  {
    size_t arow = (browoff + n0 + w*16 + fr) * (size_t)CP;
    #pragma unroll
    for (int kc=0; kc<KC; ++kc){
      aH[kc] = *(const f16x8*)&fbf[arow + kc*32 + hi*8];
      aM[kc] = *(const f16x8*)&fbf[plane + arow + kc*32 + hi*8];
    }
  }
  if (tid < 64) xn_s[tid] = xx[browoff + n0 + tid];

  float sv[5]; int si[5];
  #pragma unroll
  for (int j=0;j<5;++j){ sv[j] = -1e30f; si[j] = 0x7FFFFFFF; }

  f16x8 pf[PFH];
  float xmreg = 0.f;
  auto PFLOAD = [&](int mt){
    int m0 = mbase + (mt<<6);
    #pragma unroll
    for (int j=0;j<PFH;++j){
      int i = tid + j*256;
      int r = i/CH, cq = i - r*CH;
      pf[j] = *(const f16x8*)&fbf[(browoff + m0 + r)*(size_t)CP + cq*8];
    }
    if (tid < 64) xmreg = xx[browoff + m0 + tid];
  };
  auto WRITEPF = [&](int mt){
    int m0 = mbase + (mt<<6);
    #pragma unroll
    for (int j=0;j<PFH;++j){
      int i = tid + j*256;
      int r = i/CH, cq = i - r*CH;
      *(f16x8*)&fmb[r*SP + cq*8] = pf[j];
    }
    #pragma unroll
    for (int j=0;j<PFH;++j){
      int i = tid + j*256;
      int r = i/CH, cq = i - r*CH;
      f16x8 v = *(const f16x8*)&fbf[plane + (browoff + m0 + r)*(size_t)CP + cq*8];
      *(f16x8*)&fmb[64*SP + r*SP + cq*8] = v;
    }
    if (tid < 64) xm_s[tid] = xmreg;
  };

  PFLOAD(0);
  WRITEPF(0);
  __syncthreads();

  for (int mt = 0; mt < 16; ++mt){
    int m0 = mbase + (mt << 6);
    if (mt + 1 < 16) PFLOAD(mt + 1);

    f32x4 accH[4], accM[4];
    #pragma unroll
    for (int ct=0; ct<4; ++ct){ accH[ct] = (f32x4){0.f,0.f,0.f,0.f}; accM[ct] = accH[ct]; }
    const short* BH = fmb;
    const short* BM = fmb + 64*SP;
    #pragma unroll
    for (int kc = 0; kc < KC; ++kc){
      #pragma unroll
      for (int ct=0; ct<4; ++ct){
        int boff = (ct*16 + fr)*SP + kc*32 + hi*8;
        f16x8 bh = *(const f16x8*)&BH[boff];
        f16x8 bm = *(const f16x8*)&BM[boff];
        accH[ct] = __builtin_amdgcn_mfma_f32_16x16x32_f16(aH[kc], bh, accH[ct], 0,0,0);
        accM[ct] = __builtin_amdgcn_mfma_f32_16x16x32_f16(aM[kc], bh, accM[ct], 0,0,0);
        accM[ct] = __builtin_amdgcn_mfma_f32_16x16x32_f16(aH[kc], bm, accM[ct], 0,0,0);
      }
    }
    __syncthreads();

    #pragma unroll
    for (int reg=0; reg<4; ++reg){
      int nl = w*16 + hi*4 + reg;
      float xn = xn_s[nl];
      #pragma unroll
      for (int ct=0; ct<4; ++ct)
        dtile[nl*65 + ct*16 + fr] = 2.f*(accH[ct][reg] + IMS*accM[ct][reg]) - xn - xm_s[ct*16 + fr];
    }

    int base = myrow*65 + csub*16;
    float thr = __shfl(sv[4], lane | 3);
    unsigned qm = 0u;
    #pragma unroll
    for (int jj=0; jj<16; ++jj){
      float v = dtile[base + jj];
      qm |= (v > thr) ? (1u << jj) : 0u;
    }
    unsigned long long bal = __ballot(qm != 0u);
    while (bal){
      unsigned nib = (unsigned)((bal >> gb) & 0xFull);
      int leader = nib ? (gb + (int)__builtin_ctz(nib)) : 64;
      int bbit = (int)__builtin_ctz(qm | 0x10000u);
      float mv = dtile[base + (bbit & 15)];
      int mid = m0 + (csub << 4) + bbit;
      float cv = __shfl(mv, leader);
      int   cid = __shfl(mid, leader);
      qm = (lane == leader) ? (qm & (qm - 1u)) : qm;
      int cnt = 0;
      #pragma unroll
      for (int j=0;j<5;++j) cnt += (sv[j] >= cv) ? 1 : 0;
      cnt += __shfl_xor(cnt, 1);
      cnt += __shfl_xor(cnt, 2);
      int pos = nib ? cnt : 20;
      float pv = __shfl_up(sv[4], 1);
      int   pi = __shfl_up(si[4], 1);
      #pragma unroll
      for (int j=0;j<5;++j){
        int g = csub*5 + j;
        float ns = (g < pos) ? sv[j] : ((g == pos) ? cv : pv);
        int   ni = (g < pos) ? si[j] : ((g == pos) ? cid : pi);
        pv = sv[j]; pi = si[j];
        sv[j] = ns; si[j] = ni;
      }
      bal = __ballot(qm != 0u);
    }

    if (mt + 1 < 16){
      if constexpr (ALIAS){
        __syncthreads();
        WRITEPF(mt + 1);
        __syncthreads();
      } else {
        WRITEPF(mt + 1);
        __syncthreads();
      }
    }
  }

  size_t orow = browoff + n0 + myrow;
  float* pvo = pval + (orow*2 + mh)*KNN_K + csub*5;
  int*   pio = pidx + (orow*2 + mh)*KNN_K + csub*5;
  #pragma unroll
  for (int j=0;j<5;++j){ pvo[j] = sv[j]; pio[j] = si[j]; }
}

// ---------------- merge two sorted-20 partial lists per row ----------------
__global__ __launch_bounds__(256) void knn_merge(const float* __restrict__ pval,
                                                 const int* __restrict__ pidx,
                                                 int* __restrict__ idxout){
  int r = blockIdx.x*256 + threadIdx.x;
  if (r >= B_*N_) return;
  const float* va = pval + (size_t)r*2*KNN_K;
  const float* vb = va + KNN_K;
  const int*   ia = pidx + (size_t)r*2*KNN_K;
  const int*   ib = ia + KNN_K;
  int i=0, j=0;
  #pragma unroll
  for (int t=0;t<KNN_K;++t){
    float a = va[i], bq = vb[j];
    bool ta = (a >= bq);   // tie -> half 0 (lower ids)
    idxout[(size_t)r*KNN_K + t] = ta ? ia[i] : ib[j];
    i += ta ? 1 : 0; j += ta ? 0 : 1;
  }
}

// ---------------- combined P+Q GEMM (fp16 2-plane), fp32 outputs ----------------
template<int CP>
__global__ __launch_bounds__(256) void gemm_pq2(const short* __restrict__ fbf, size_t plane,
                                                const float* __restrict__ Wsrc, int Cin,
                                                float* __restrict__ P, float* __restrict__ Qo, int O){
  constexpr int BK = (CP < 64) ? CP : 64;
  constexpr int SP = BK + 8;
  __shared__ short Ah[64*SP];
  __shared__ short Am[64*SP];
  __shared__ short WAh[64*SP];
  __shared__ short WAm[64*SP];
  __shared__ short WQh[64*SP];
  __shared__ short WQm[64*SP];
  int obl = O >> 6;
  int bo = ((int)blockIdx.x % obl) << 6;
  int bm = ((int)blockIdx.x / obl) << 6;
  int tid = threadIdx.x;
  int w = tid >> 6, lane = tid & 63;
  int fr = lane & 15, hi = lane >> 4;
  f32x4 aPH[4], aPM[4], aQH[4], aQM[4];
  #pragma unroll
  for (int ct=0; ct<4; ++ct){
    aPH[ct] = (f32x4){0.f,0.f,0.f,0.f};
    aPM[ct] = aPH[ct]; aQH[ct] = aPH[ct]; aQM[ct] = aPH[ct];
  }

  for (int k0=0; k0<CP; k0+=BK){
    __syncthreads();
    for (int i=tid; i < 64*(BK/8); i += 256){
      int r = i/(BK/8), cq = i%(BK/8);
      size_t src = ((size_t)bm + r)*CP + k0 + cq*8;
      *(f16x8*)&Ah[r*SP + cq*8] = *(const f16x8*)&fbf[src];
      *(f16x8*)&Am[r*SP + cq*8] = *(const f16x8*)&fbf[plane + src];
    }
    for (int i=tid; i < 64*(BK/8); i += 256){
      int r = i/(BK/8), cq = i%(BK/8);
      f16x8 vah, vam, vqh, vqm;
      #pragma unroll
      for (int e=0;e<8;++e){
        int c = k0 + cq*8 + e;
        float wa = 0.f, wqv = 0.f;
        if (c < Cin){
          wa  = Wsrc[(size_t)(bo + r)*2*Cin + c];
          wqv = Wsrc[(size_t)(bo + r)*2*Cin + Cin + c] - wa;
        }
        _Float16 ha = (_Float16)wa;
        vah[e] = ha;
        vam[e] = (_Float16)((wa - (float)ha) * 2048.f);
        _Float16 hq = (_Float16)wqv;
        vqh[e] = hq;
        vqm[e] = (_Float16)((wqv - (float)hq) * 2048.f);
      }
      *(f16x8*)&WAh[r*SP + cq*8] = vah;
      *(f16x8*)&WAm[r*SP + cq*8] = vam;
      *(f16x8*)&WQh[r*SP + cq*8] = vqh;
      *(f16x8*)&WQm[r*SP + cq*8] = vqm;
    }
    __syncthreads();
    #pragma unroll
    for (int kc=0; kc<BK/32; ++kc){
      f16x8 ah = *(const f16x8*)&Ah[(w*16 + fr)*SP + kc*32 + hi*8];
      f16x8 am = *(const f16x8*)&Am[(w*16 + fr)*SP + kc*32 + hi*8];
      #pragma unroll
      for (int ct=0; ct<4; ++ct){
        int boff = (ct*16 + fr)*SP + kc*32 + hi*8;
        f16x8 bh = *(const f16x8*)&WAh[boff];
        f16x8 bm = *(const f16x8*)&WAm[boff];
        f16x8 qh = *(const f16x8*)&WQh[boff];
        f16x8 qm = *(const f16x8*)&WQm[boff];
        aPH[ct] = __builtin_amdgcn_mfma_f32_16x16x32_f16(ah, bh, aPH[ct], 0,0,0);
        aPM[ct] = __builtin_amdgcn_mfma_f32_16x16x32_f16(am, bh, aPM[ct], 0,0,0);
        aPM[ct] = __builtin_amdgcn_mfma_f32_16x16x32_f16(ah, bm, aPM[ct], 0,0,0);
        aQH[ct] = __builtin_amdgcn_mfma_f32_16x16x32_f16(ah, qh, aQH[ct], 0,0,0);
        aQM[ct] = __builtin_amdgcn_mfma_f32_16x16x32_f16(am, qh, aQM[ct], 0,0,0);
        aQM[ct] = __builtin_amdgcn_mfma_f32_16x16x32_f16(ah, qm, aQM[ct], 0,0,0);
      }
    }
  }
  #pragma unroll
  for (int ct=0; ct<4; ++ct)
    #pragma unroll
    for (int reg=0; reg<4; ++reg){
      int row = bm + w*16 + hi*4 + reg;
      size_t o = (size_t)row*O + bo + ct*16 + fr;
      P[o]  = aPH[ct][reg] + IMS*aPM[ct][reg];
      Qo[o] = aQH[ct][reg] + IMS*aQM[ct][reg];
    }
}

// ---------------- conv5 GEMM (bf16 staged) with fused BN stats + signed max epilogue ----------------
__global__ __launch_bounds__(256) void gemm_bf16_stats(const float* __restrict__ A,
                                                       const float* __restrict__ Wt,
                                                       const float* __restrict__ g5,
                                                       float* __restrict__ sums,
                                                       float* __restrict__ sumsq,
                                                       unsigned* __restrict__ maxenc){
  __shared__ short As[128*72];
  __shared__ short Bs[64*72];
  __shared__ float s1[64], s2[64];
  int bm = (int)(blockIdx.x >> 3) << 7;
  int bo = (int)(blockIdx.x & 7) << 6;
  int tid = threadIdx.x;
  int w = tid >> 6, lane = tid & 63;
  int fr = lane & 15, hi = lane >> 4;
  f32x4 acc[2][4];
  #pragma unroll
  for (int g=0; g<2; ++g)
    #pragma unroll
    for (int ct=0; ct<4; ++ct) acc[g][ct] = (f32x4){0.f,0.f,0.f,0.f};

  for (int k0=0; k0<512; k0+=64){
    __syncthreads();
    #pragma unroll 2
    for (int i = tid; i < 1024; i += 256){
      int r = i >> 3, cq = i & 7;
      const float* src = &A[(size_t)(bm + r)*512 + k0 + cq*8];
      bf16x8 v;
      #pragma unroll
      for (int e=0;e<8;++e) v[e] = bfbits(src[e]);
      *(bf16x8*)&As[r*72 + cq*8] = v;
    }
    #pragma unroll 2
    for (int i = tid; i < 512; i += 256){
      int r = i >> 3, cq = i & 7;
      const float* src = &Wt[(size_t)(bo + r)*512 + k0 + cq*8];
      bf16x8 v;
      #pragma unroll
      for (int e=0;e<8;++e) v[e] = bfbits(src[e]);
      *(bf16x8*)&Bs[r*72 + cq*8] = v;
    }
    __syncthreads();
    #pragma unroll
    for (int kc=0; kc<2; ++kc){
      bf16x8 a0 = *(const bf16x8*)&As[(w*32 +      fr)*72 + kc*32 + hi*8];
      bf16x8 a1 = *(const bf16x8*)&As[(w*32 + 16 + fr)*72 + kc*32 + hi*8];
      #pragma unroll
      for (int ct=0; ct<4; ++ct){
        bf16x8 bb = *(const bf16x8*)&Bs[(ct*16 + fr)*72 + kc*32 + hi*8];
        acc[0][ct] = __builtin_amdgcn_mfma_f32_16x16x32_bf16(a0, bb, acc[0][ct], 0,0,0);
        acc[1][ct] = __builtin_amdgcn_mfma_f32_16x16x32_bf16(a1, bb, acc[1][ct], 0,0,0);
      }
    }
  }

  __syncthreads();
  if (tid < 64){ s1[tid] = 0.f; s2[tid] = 0.f; }
  __syncthreads();
  int bidx = bm >> 11;
  #pragma unroll
  for (int ct=0; ct<4; ++ct){
    int o = bo + ct*16 + fr;
    float ga = g5[o];
    float s = 0.f, ss = 0.f, mx = -1e30f;
    #pragma unroll
    for (int g=0; g<2; ++g)
      #pragma unroll
      for (int reg=0; reg<4; ++reg){
        float v = acc[g][ct][reg];
        s += v; ss += v*v;
        float sel = ga >= 0.f ? v : -v;
        mx = fmaxf(mx, sel);
      }
    s  += __shfl_xor(s, 16);  s  += __shfl_xor(s, 32);
    ss += __shfl_xor(ss, 16); ss += __shfl_xor(ss, 32);
    mx = fmaxf(mx, __shfl_xor(mx, 16)); mx = fmaxf(mx, __shfl_xor(mx, 32));
    if (hi == 0){
      atomicAdd(&s1[ct*16 + fr], s);
      atomicAdd(&s2[ct*16 + fr], ss);
      atomicMax(&maxenc[bidx*512 + o], encf(mx));
    }
  }
  __syncthreads();
  if (tid < 64){
    atomicAdd(&sums[bo + tid],  s1[tid]);
    atomicAdd(&sumsq[bo + tid], s2[tid]);
  }
}

__global__ void zero_f_kernel(float* p, int n){
  int i = blockIdx.x*blockDim.x + threadIdx.x;
  if (i < n) p[i] = 0.f;
}
__global__ void zero_u_kernel(unsigned* p, int n){
  int i = blockIdx.x*blockDim.x + threadIdx.x;
  if (i < n) p[i] = 0u;
}

// ---------------- edge aggregation (fp32 P/Q/S) ----------------
__global__ __launch_bounds__(256) void edge_agg(const float* __restrict__ P, const float* __restrict__ Q,
      const int* __restrict__ idx, const float* __restrict__ gamma,
      float* __restrict__ S, float* __restrict__ sums, float* __restrict__ sumsq, int O){
  const int ROWS = 64;
  int rpi = 256 / O;
  int iters = ROWS / rpi;
  int row0 = blockIdx.x * ROWS;
  int tid = threadIdx.x;
  int o  = tid % O;
  int rl = tid / O;
  int b  = row0 / N_;
  __shared__ int sidx[4][KNN_K];
  __shared__ float s1[256], s2[256];
  float g = gamma[o];
  float csum=0.f, csumsq=0.f;
  for (int it=0; it<iters; ++it){
    __syncthreads();
    if (tid < KNN_K*rpi) sidx[tid/KNN_K][tid%KNN_K] = idx[(size_t)(row0 + it*rpi)*KNN_K + tid];
    __syncthreads();
    int row = row0 + it*rpi + rl;
    float q = Q[(size_t)row*O + o];
    float mx=-1e30f, mn=1e30f, s=0.f, ss=0.f;
    #pragma unroll
    for (int k=0;k<KNN_K;++k){
      int m = sidx[rl][k];
      float p = P[((size_t)b*N_ + m)*O + o];
      mx = fmaxf(mx,p); mn = fminf(mn,p);
      float y = p + q; s += y; ss += y*y;
    }
    csum += s; csumsq += ss;
    S[(size_t)row*O + o] = (g >= 0.f ? mx : mn) + q;
  }
  s1[tid]=0.f; s2[tid]=0.f;
  __syncthreads();
  atomicAdd(&s1[o], csum); atomicAdd(&s2[o], csumsq);
  __syncthreads();
  if (tid < O){ atomicAdd(&sums[tid], s1[tid]); atomicAdd(&sumsq[tid], s2[tid]); }
}

// ---------------- BN finalize ----------------
__global__ void bn_finalize(const float* __restrict__ sums, const float* __restrict__ sumsq,
                            const float* __restrict__ gamma, const float* __restrict__ beta,
                            float invM, float* __restrict__ scale, float* __restrict__ shift, int O){
  int o = blockIdx.x*blockDim.x + threadIdx.x;
  if (o >= O) return;
  float mu = sums[o]*invM;
  float var = sumsq[o]*invM - mu*mu;
  float rs = rsqrtf(var + EPS_);
  float sc = gamma[o]*rs;
  scale[o] = sc; shift[o] = beta[o] - mu*sc;
}

// ---------------- apply affine+lrelu, write cat; optionally emit next layer's planes + xx ----------------
// EMIT: also write fp16 h/m planes (stride O, plane size M*O shorts) and per-row xx.
// Each 256-thread block covers whole rows (O divides 256), so xx needs no global atomics.
template<int O, bool EMIT>
__global__ __launch_bounds__(256) void apply_write_f(const float* __restrict__ S, const float* __restrict__ scale,
                            const float* __restrict__ shift, float* __restrict__ cat, int off,
                            short* __restrict__ fbf, float* __restrict__ xx){
  __shared__ float rxx[256/O >= 1 ? 256/O : 1];
  int i = blockIdx.x*256 + threadIdx.x;
  int row = i / O, o = i - row*O;
  int rl = threadIdx.x / O;
  if (EMIT){
    if (threadIdx.x < 256/O) rxx[threadIdx.x] = 0.f;
    __syncthreads();
  }
  float v = S[i]*scale[o] + shift[o];
  v = lrelu(v);
  cat[(size_t)row*512 + off + o] = v;
  if (EMIT){
    short h = h16(v);
    short m = h16((v - h2f(h)) * 2048.f);
    size_t po = (size_t)row*O + o;
    fbf[po] = h;
    fbf[(size_t)B_*N_*O + po] = m;
    atomicAdd(&rxx[rl], v*v);
    __syncthreads();
    if (threadIdx.x < 256/O) xx[blockIdx.x*(256/O) + threadIdx.x] = rxx[threadIdx.x];
  }
}

// ---------------- pool ----------------
__global__ void pool_kernel(const unsigned* __restrict__ maxenc, const float* __restrict__ scale,
                            const float* __restrict__ shift, const float* __restrict__ g5,
                            float* __restrict__ pooled){
  int i = blockIdx.x*blockDim.x + threadIdx.x;
  if (i >= B_*512) return;
  int o = i & 511;
  float t = decf(maxenc[i]);
  float y = g5[o] >= 0.f ? t : -t;
  pooled[i] = lrelu(y*scale[o] + shift[o]);
}

// ---------------- final projection ----------------
__global__ void final_mm(const float* __restrict__ pooled, const float* __restrict__ we,
                         float* __restrict__ out){
  int i = blockIdx.x*blockDim.x + threadIdx.x;
  if (i >= B_*128) return;
  int b = i >> 7, j = i & 127;
  const float4* pp = (const float4*)(pooled + (size_t)b*512);
  const float4* wp = (const float4*)(we + (size_t)j*512);
  float s = 0.f;
  for (int c=0;c<128;++c){
    float4 a = pp[c], w = wp[c];
    s += a.x*w.x + a.y*w.y + a.z*w.z + a.w*w.w;
  }
  out[i] = s;
}

// ---------------- driver ----------------
struct Ws {
  float* cat; float* P; float* Q; float* S; int* idx; float* xx;
  float* sums; float* sumsq; float* scale; float* shift;
  unsigned* maxenc; float* pooled; short* fbf;
  float* pval; int* pidx;
};

// Layer k: planes for knn already in W.fbf (written by previous apply or convert).
// apply_write emits planes for next layer when EMIT (O = next CP).
template<int C, int CP, int O, bool EMIT>
static void run_layer(const Ws& W, int O_rt, const float* w, const float* g, const float* bt,
                      int off_out, hipStream_t stream){
  const int M = B_*N_;
  size_t plane = (size_t)M*CP;
  knn_mfma<CP><<<B_*(N_/64)*2, 256, 0, stream>>>(W.fbf, plane, W.xx, W.pval, W.pidx);
  knn_merge<<<(M+255)/256, 256, 0, stream>>>(W.pval, W.pidx, W.idx);
  int grid = (M/64)*(O/64);
  gemm_pq2<CP><<<grid, 256, 0, stream>>>(W.fbf, plane, w, C, W.P, W.Q, O);
  zero_f_kernel<<<4, 256, 0, stream>>>(W.sums, 1024);
  edge_agg<<<M/64, 256, 0, stream>>>(W.P, W.Q, W.idx, g, W.S, W.sums, W.sumsq, O);
  bn_finalize<<<(O+255)/256, 256, 0, stream>>>(W.sums, W.sumsq, g, bt,
                                               1.f/((float)M*KNN_K), W.scale, W.shift, O);
  apply_write_f<O, EMIT><<<(M*O)/256, 256, 0, stream>>>(W.S, W.scale, W.shift, W.cat, off_out,
                                                        W.fbf, W.xx);
}

extern "C" void kernel_launch(void* const* d_in, const int* in_sizes, int n_in,
                              void* d_out, int out_size, void* d_ws, size_t ws_size,
                              hipStream_t stream) {
  const float* x  = (const float*)d_in[0];
  const float* w1 = (const float*)d_in[1];
  const float* g1 = (const float*)d_in[2];
  const float* b1 = (const float*)d_in[3];
  const float* w2 = (const float*)d_in[4];
  const float* g2 = (const float*)d_in[5];
  const float* b2 = (const float*)d_in[6];
  const float* w3 = (const float*)d_in[7];
  const float* g3 = (const float*)d_in[8];
  const float* b3 = (const float*)d_in[9];
  const float* w4 = (const float*)d_in[10];
  const float* g4 = (const float*)d_in[11];
  const float* b4 = (const float*)d_in[12];
  const float* w5 = (const float*)d_in[13];
  const float* g5 = (const float*)d_in[14];
  const float* b5 = (const float*)d_in[15];
  const float* we = (const float*)d_in[16];

  char* ws = (char*)d_ws;
  Ws W;
  size_t off = 0;
  W.cat   = (float*)(ws + off); off += (size_t)16*2048*512*4;   // 67.1 MB
  W.P     = (float*)(ws + off); off += (size_t)16*2048*256*4;   // 33.5 MB
  W.Q     = (float*)(ws + off); off += (size_t)16*2048*256*4;   // 33.5 MB
  char* R = ws + off;            off += (size_t)16*2048*256*4;  // 33.5 MB: S | planes
  W.idx   = (int*)  (ws + off); off += (size_t)16*2048*20*4;
  W.xx    = (float*)(ws + off); off += (size_t)16*2048*4;
  W.sums  = (float*)(ws + off); off += 512*4;
  W.sumsq = (float*)(ws + off); off += 512*4;
  W.scale = (float*)(ws + off); off += 512*4;
  W.shift = (float*)(ws + off); off += 512*4;
  W.maxenc= (unsigned*)(ws + off); off += (size_t)16*512*4;
  W.pooled= (float*)(ws + off); off += (size_t)16*512*4;
  W.S     = (float*)R;                              // S(k): first M*O_k*4 bytes of R
  W.fbf   = (short*)(R + (size_t)16*2048*128*4);    // planes: second half of R (16.78 MB)
  W.pval  = W.Q;                                    // partials live [knn, merge]
  W.pidx  = (int*)(W.Q + (size_t)2*16*2048*KNN_K);

  const int M = B_*N_;

  // layer 1: convert from x (C=3 -> CP=32 planes)
  convert_kernel<3, 32><<<M/4, 256, 0, stream>>>(x, 3, W.fbf, (size_t)M*32, W.xx);
  run_layer<3,   32,  64, true >(W, 64,  w1, g1, b1, 0,   stream);   // emits planes CP=64
  run_layer<64,  64,  64, true >(W, 64,  w2, g2, b2, 64,  stream);   // emits planes CP=64
  run_layer<64,  64, 128, true >(W, 128, w3, g3, b3, 128, stream);   // emits planes CP=128
  run_layer<128,128, 256, false>(W, 256, w4, g4, b4, 256, stream);   // terminal

  // conv5 with fused BN-stats + signed-max epilogue (no y5 materialization)
  zero_f_kernel<<<4, 256, 0, stream>>>(W.sums, 1024);
  zero_u_kernel<<<32, 256, 0, stream>>>(W.maxenc, 16*512);
  gemm_bf16_stats<<<(M/128)*8, 256, 0, stream>>>(W.cat, w5, g5, W.sums, W.sumsq, W.maxenc);
  bn_finalize<<<2, 256, 0, stream>>>(W.sums, W.sumsq, g5, b5, 1.f/(float)M, W.scale, W.shift, 512);
  pool_kernel<<<(16*512+255)/256, 256, 0, stream>>>(W.maxenc, W.scale, W.shift, g5, W.pooled);
  final_mm<<<(16*128+255)/256, 256, 0, stream>>>(W.pooled, we, (float*)d_out);
}

// Round 16
// 1156.342 us; speedup vs baseline: 1.0597x; 1.0297x over previous
//
#include <hip/hip_runtime.h>
#include <hip/hip_bf16.h>
#include <cstdint>

#define B_ 16
#define N_ 2048
#define KNN_K 20
#define EPS_ 1e-5f
#define SLOPE_ 0.2f
#define IMS 4.8828125e-4f   // 1/2048

typedef __attribute__((ext_vector_type(4))) float f32x4;
typedef __attribute__((ext_vector_type(8))) short bf16x8;
typedef __attribute__((ext_vector_type(8))) _Float16 f16x8;

static __device__ __forceinline__ float lrelu(float v){ return v > 0.f ? v : SLOPE_*v; }

static __device__ __forceinline__ unsigned encf(float f){
  unsigned b = __float_as_uint(f);
  return (b & 0x80000000u) ? ~b : (b | 0x80000000u);
}
static __device__ __forceinline__ float decf(unsigned u){
  unsigned b = (u & 0x80000000u) ? (u ^ 0x80000000u) : ~u;
  return __uint_as_float(b);
}
static __device__ __forceinline__ short bfbits(float v){
  __hip_bfloat16 h = __float2bfloat16(v);
  return *reinterpret_cast<short*>(&h);
}
static __device__ __forceinline__ short h16(float v){
  _Float16 h = (_Float16)v;
  return *reinterpret_cast<short*>(&h);
}
static __device__ __forceinline__ float h2f(short s){
  _Float16 h = *reinterpret_cast<_Float16*>(&s);
  return (float)h;
}

// ---------------- convert: f -> 2 fp16 planes (h, (v-h)*2048) + xx (fp32) ----------------
template<int C, int CP>
__global__ __launch_bounds__(256) void convert_kernel(const float* __restrict__ f, int lda,
                                                      short* __restrict__ fbf, size_t plane,
                                                      float* __restrict__ xx){
  int wid  = (blockIdx.x * 256 + threadIdx.x) >> 6;   // one wave per row
  int lane = threadIdx.x & 63;
  if (wid >= B_*N_) return;
  const float* p = f + (size_t)wid*lda;
  float s = 0.f;
  for (int c = lane; c < CP; c += 64){
    float v = (c < C) ? p[c] : 0.f;
    short h = h16(v);
    short m = h16((v - h2f(h)) * 2048.f);
    size_t o = (size_t)wid*CP + c;
    fbf[o] = h;
    fbf[plane + o] = m;
    s += v*v;
  }
  #pragma unroll
  for (int off=32; off; off>>=1) s += __shfl_down(s, off);
  if (lane==0) xx[wid] = s;
}

// ---------------- fused MFMA distance (fp16 2-plane) + wave-coop top-20, m-split ----------------
// Non-aliased dtile: only 2 barriers per tile (post-MFMA fmb-drain, post-WRITEPF fmb-ready).
// Occupancy is register-bound (2 blocks/CU), so the extra LDS is free.
template<int CP>
__global__ __launch_bounds__(256, 2) void knn_mfma(const short* __restrict__ fbf, size_t plane,
                                                const float* __restrict__ xx,
                                                float* __restrict__ pval, int* __restrict__ pidx){
  constexpr int SP = CP + 8;          // shorts per LDS row
  constexpr int CH = CP/8;
  constexpr int KC = CP/32;
  constexpr int PFH = CP/32;          // 16B chunks per thread, H plane only
  constexpr int FMBS = 2*64*SP;       // fmb shorts
  __shared__ __align__(16) short fmb[FMBS];
  __shared__ float dtile[64*65];
  __shared__ float xn_s[64], xm_s[64];

  int b   = blockIdx.x >> 6;
  int rem = blockIdx.x & 63;
  int n0  = (rem >> 1) << 6;
  int mh  = rem & 1;
  int mbase = mh << 10;
  int tid = threadIdx.x;
  int w    = tid >> 6;
  int lane = tid & 63;
  int fr = lane & 15, hi = lane >> 4;
  int r_loc = lane >> 2, csub = lane & 3;
  int gb = lane & 60;
  int myrow = w*16 + r_loc;
  size_t browoff = (size_t)b * N_;

  f16x8 aH[KC], aM[KC];
  {
    size_t arow = (browoff + n0 + w*16 + fr) * (size_t)CP;
    #pragma unroll
    for (int kc=0; kc<KC; ++kc){
      aH[kc] = *(const f16x8*)&fbf[arow + kc*32 + hi*8];
      aM[kc] = *(const f16x8*)&fbf[plane + arow + kc*32 + hi*8];
    }
  }
  if (tid < 64) xn_s[tid] = xx[browoff + n0 + tid];

  float sv[5]; int si[5];
  #pragma unroll
  for (int j=0;j<5;++j){ sv[j] = -1e30f; si[j] = 0x7FFFFFFF; }

  f16x8 pf[PFH];
  float xmreg = 0.f;
  auto PFLOAD = [&](int mt){
    int m0 = mbase + (mt<<6);
    #pragma unroll
    for (int j=0;j<PFH;++j){
      int i = tid + j*256;
      int r = i/CH, cq = i - r*CH;
      pf[j] = *(const f16x8*)&fbf[(browoff + m0 + r)*(size_t)CP + cq*8];
    }
    if (tid < 64) xmreg = xx[browoff + m0 + tid];
  };
  auto WRITEPF = [&](int mt){
    int m0 = mbase + (mt<<6);
    #pragma unroll
    for (int j=0;j<PFH;++j){
      int i = tid + j*256;
      int r = i/CH, cq = i - r*CH;
      *(f16x8*)&fmb[r*SP + cq*8] = pf[j];
    }
    #pragma unroll
    for (int j=0;j<PFH;++j){
      int i = tid + j*256;
      int r = i/CH, cq = i - r*CH;
      f16x8 v = *(const f16x8*)&fbf[plane + (browoff + m0 + r)*(size_t)CP + cq*8];
      *(f16x8*)&fmb[64*SP + r*SP + cq*8] = v;
    }
    if (tid < 64) xm_s[tid] = xmreg;
  };

  PFLOAD(0);
  WRITEPF(0);
  __syncthreads();

  for (int mt = 0; mt < 16; ++mt){
    int m0 = mbase + (mt << 6);
    if (mt + 1 < 16) PFLOAD(mt + 1);

    f32x4 accH[4], accM[4];
    #pragma unroll
    for (int ct=0; ct<4; ++ct){ accH[ct] = (f32x4){0.f,0.f,0.f,0.f}; accM[ct] = accH[ct]; }
    const short* BH = fmb;
    const short* BM = fmb + 64*SP;
    #pragma unroll
    for (int kc = 0; kc < KC; ++kc){
      #pragma unroll
      for (int ct=0; ct<4; ++ct){
        int boff = (ct*16 + fr)*SP + kc*32 + hi*8;
        f16x8 bh = *(const f16x8*)&BH[boff];
        f16x8 bm = *(const f16x8*)&BM[boff];
        accH[ct] = __builtin_amdgcn_mfma_f32_16x16x32_f16(aH[kc], bh, accH[ct], 0,0,0);
        accM[ct] = __builtin_amdgcn_mfma_f32_16x16x32_f16(aM[kc], bh, accM[ct], 0,0,0);
        accM[ct] = __builtin_amdgcn_mfma_f32_16x16x32_f16(aH[kc], bm, accM[ct], 0,0,0);
      }
    }
    __syncthreads();   // all fmb reads done -> WRITEPF below may overwrite

    // dtile (separate LDS region; same-wave RAW only)
    #pragma unroll
    for (int reg=0; reg<4; ++reg){
      int nl = w*16 + hi*4 + reg;
      float xn = xn_s[nl];
      #pragma unroll
      for (int ct=0; ct<4; ++ct)
        dtile[nl*65 + ct*16 + fr] = 2.f*(accH[ct][reg] + IMS*accM[ct][reg]) - xn - xm_s[ct*16 + fr];
    }

    // wave-cooperative selection (r8-proven, bit-exact)
    int base = myrow*65 + csub*16;
    float thr = __shfl(sv[4], lane | 3);
    unsigned qm = 0u;
    #pragma unroll
    for (int jj=0; jj<16; ++jj){
      float v = dtile[base + jj];
      qm |= (v > thr) ? (1u << jj) : 0u;
    }
    unsigned long long bal = __ballot(qm != 0u);
    while (bal){
      unsigned nib = (unsigned)((bal >> gb) & 0xFull);
      int leader = nib ? (gb + (int)__builtin_ctz(nib)) : 64;
      int bbit = (int)__builtin_ctz(qm | 0x10000u);
      float mv = dtile[base + (bbit & 15)];
      int mid = m0 + (csub << 4) + bbit;
      float cv = __shfl(mv, leader);
      int   cid = __shfl(mid, leader);
      qm = (lane == leader) ? (qm & (qm - 1u)) : qm;
      int cnt = 0;
      #pragma unroll
      for (int j=0;j<5;++j) cnt += (sv[j] >= cv) ? 1 : 0;
      cnt += __shfl_xor(cnt, 1);
      cnt += __shfl_xor(cnt, 2);
      int pos = nib ? cnt : 20;
      float pv = __shfl_up(sv[4], 1);
      int   pi = __shfl_up(si[4], 1);
      #pragma unroll
      for (int j=0;j<5;++j){
        int g = csub*5 + j;
        float ns = (g < pos) ? sv[j] : ((g == pos) ? cv : pv);
        int   ni = (g < pos) ? si[j] : ((g == pos) ? cid : pi);
        pv = sv[j]; pi = si[j];
        sv[j] = ns; si[j] = ni;
      }
      bal = __ballot(qm != 0u);
    }

    if (mt + 1 < 16){
      WRITEPF(mt + 1);   // fmb disjoint from dtile: no extra barrier needed
      __syncthreads();   // fmb(t+1) + xm_s ready
    }
  }

  size_t orow = browoff + n0 + myrow;
  float* pvo = pval + (orow*2 + mh)*KNN_K + csub*5;
  int*   pio = pidx + (orow*2 + mh)*KNN_K + csub*5;
  #pragma unroll
  for (int j=0;j<5;++j){ pvo[j] = sv[j]; pio[j] = si[j]; }
}

// ---------------- merge two sorted-20 partial lists per row ----------------
__global__ __launch_bounds__(256) void knn_merge(const float* __restrict__ pval,
                                                 const int* __restrict__ pidx,
                                                 int* __restrict__ idxout){
  int r = blockIdx.x*256 + threadIdx.x;
  if (r >= B_*N_) return;
  const float* va = pval + (size_t)r*2*KNN_K;
  const float* vb = va + KNN_K;
  const int*   ia = pidx + (size_t)r*2*KNN_K;
  const int*   ib = ia + KNN_K;
  int i=0, j=0;
  #pragma unroll
  for (int t=0;t<KNN_K;++t){
    float a = va[i], bq = vb[j];
    bool ta = (a >= bq);   // tie -> half 0 (lower ids)
    idxout[(size_t)r*KNN_K + t] = ta ? ia[i] : ib[j];
    i += ta ? 1 : 0; j += ta ? 0 : 1;
  }
}

// ---------------- combined P+Q GEMM (fp16 2-plane): A staged once, wq = wB - wA inline ----------------
template<int CP>
__global__ __launch_bounds__(256) void gemm_pq2(const short* __restrict__ fbf, size_t plane,
                                                const float* __restrict__ Wsrc, int Cin,
                                                float* __restrict__ P, float* __restrict__ Qo, int O){
  constexpr int BK = (CP < 64) ? CP : 64;
  constexpr int SP = BK + 8;
  __shared__ short Ah[64*SP];
  __shared__ short Am[64*SP];
  __shared__ short WAh[64*SP];
  __shared__ short WAm[64*SP];
  __shared__ short WQh[64*SP];
  __shared__ short WQm[64*SP];
  int obl = O >> 6;
  int bo = ((int)blockIdx.x % obl) << 6;
  int bm = ((int)blockIdx.x / obl) << 6;
  int tid = threadIdx.x;
  int w = tid >> 6, lane = tid & 63;
  int fr = lane & 15, hi = lane >> 4;
  f32x4 aPH[4], aPM[4], aQH[4], aQM[4];
  #pragma unroll
  for (int ct=0; ct<4; ++ct){
    aPH[ct] = (f32x4){0.f,0.f,0.f,0.f};
    aPM[ct] = aPH[ct]; aQH[ct] = aPH[ct]; aQM[ct] = aPH[ct];
  }

  for (int k0=0; k0<CP; k0+=BK){
    __syncthreads();
    for (int i=tid; i < 64*(BK/8); i += 256){
      int r = i/(BK/8), cq = i%(BK/8);
      size_t src = ((size_t)bm + r)*CP + k0 + cq*8;
      *(f16x8*)&Ah[r*SP + cq*8] = *(const f16x8*)&fbf[src];
      *(f16x8*)&Am[r*SP + cq*8] = *(const f16x8*)&fbf[plane + src];
    }
    for (int i=tid; i < 64*(BK/8); i += 256){
      int r = i/(BK/8), cq = i%(BK/8);
      f16x8 vah, vam, vqh, vqm;
      #pragma unroll
      for (int e=0;e<8;++e){
        int c = k0 + cq*8 + e;
        float wa = 0.f, wqv = 0.f;
        if (c < Cin){
          wa  = Wsrc[(size_t)(bo + r)*2*Cin + c];
          wqv = Wsrc[(size_t)(bo + r)*2*Cin + Cin + c] - wa;
        }
        _Float16 ha = (_Float16)wa;
        vah[e] = ha;
        vam[e] = (_Float16)((wa - (float)ha) * 2048.f);
        _Float16 hq = (_Float16)wqv;
        vqh[e] = hq;
        vqm[e] = (_Float16)((wqv - (float)hq) * 2048.f);
      }
      *(f16x8*)&WAh[r*SP + cq*8] = vah;
      *(f16x8*)&WAm[r*SP + cq*8] = vam;
      *(f16x8*)&WQh[r*SP + cq*8] = vqh;
      *(f16x8*)&WQm[r*SP + cq*8] = vqm;
    }
    __syncthreads();
    #pragma unroll
    for (int kc=0; kc<BK/32; ++kc){
      f16x8 ah = *(const f16x8*)&Ah[(w*16 + fr)*SP + kc*32 + hi*8];
      f16x8 am = *(const f16x8*)&Am[(w*16 + fr)*SP + kc*32 + hi*8];
      #pragma unroll
      for (int ct=0; ct<4; ++ct){
        int boff = (ct*16 + fr)*SP + kc*32 + hi*8;
        f16x8 bh = *(const f16x8*)&WAh[boff];
        f16x8 bm = *(const f16x8*)&WAm[boff];
        f16x8 qh = *(const f16x8*)&WQh[boff];
        f16x8 qm = *(const f16x8*)&WQm[boff];
        aPH[ct] = __builtin_amdgcn_mfma_f32_16x16x32_f16(ah, bh, aPH[ct], 0,0,0);
        aPM[ct] = __builtin_amdgcn_mfma_f32_16x16x32_f16(am, bh, aPM[ct], 0,0,0);
        aPM[ct] = __builtin_amdgcn_mfma_f32_16x16x32_f16(ah, bm, aPM[ct], 0,0,0);
        aQH[ct] = __builtin_amdgcn_mfma_f32_16x16x32_f16(ah, qh, aQH[ct], 0,0,0);
        aQM[ct] = __builtin_amdgcn_mfma_f32_16x16x32_f16(am, qh, aQM[ct], 0,0,0);
        aQM[ct] = __builtin_amdgcn_mfma_f32_16x16x32_f16(ah, qm, aQM[ct], 0,0,0);
      }
    }
  }
  #pragma unroll
  for (int ct=0; ct<4; ++ct)
    #pragma unroll
    for (int reg=0; reg<4; ++reg){
      int row = bm + w*16 + hi*4 + reg;
      size_t o = (size_t)row*O + bo + ct*16 + fr;
      P[o]  = aPH[ct][reg] + IMS*aPM[ct][reg];
      Qo[o] = aQH[ct][reg] + IMS*aQM[ct][reg];
    }
}

// ---------------- conv5 GEMM (bf16 staged) with fused BN stats + signed max epilogue ----------------
__global__ __launch_bounds__(256) void gemm_bf16_stats(const float* __restrict__ A,
                                                       const float* __restrict__ Wt,
                                                       const float* __restrict__ g5,
                                                       float* __restrict__ sums,
                                                       float* __restrict__ sumsq,
                                                       unsigned* __restrict__ maxenc){
  __shared__ short As[128*72];
  __shared__ short Bs[64*72];
  __shared__ float s1[64], s2[64];
  int bm = (int)(blockIdx.x >> 3) << 7;
  int bo = (int)(blockIdx.x & 7) << 6;
  int tid = threadIdx.x;
  int w = tid >> 6, lane = tid & 63;
  int fr = lane & 15, hi = lane >> 4;
  f32x4 acc[2][4];
  #pragma unroll
  for (int g=0; g<2; ++g)
    #pragma unroll
    for (int ct=0; ct<4; ++ct) acc[g][ct] = (f32x4){0.f,0.f,0.f,0.f};

  for (int k0=0; k0<512; k0+=64){
    __syncthreads();
    #pragma unroll 2
    for (int i = tid; i < 1024; i += 256){
      int r = i >> 3, cq = i & 7;
      const float* src = &A[(size_t)(bm + r)*512 + k0 + cq*8];
      bf16x8 v;
      #pragma unroll
      for (int e=0;e<8;++e) v[e] = bfbits(src[e]);
      *(bf16x8*)&As[r*72 + cq*8] = v;
    }
    #pragma unroll 2
    for (int i = tid; i < 512; i += 256){
      int r = i >> 3, cq = i & 7;
      const float* src = &Wt[(size_t)(bo + r)*512 + k0 + cq*8];
      bf16x8 v;
      #pragma unroll
      for (int e=0;e<8;++e) v[e] = bfbits(src[e]);
      *(bf16x8*)&Bs[r*72 + cq*8] = v;
    }
    __syncthreads();
    #pragma unroll
    for (int kc=0; kc<2; ++kc){
      bf16x8 a0 = *(const bf16x8*)&As[(w*32 +      fr)*72 + kc*32 + hi*8];
      bf16x8 a1 = *(const bf16x8*)&As[(w*32 + 16 + fr)*72 + kc*32 + hi*8];
      #pragma unroll
      for (int ct=0; ct<4; ++ct){
        bf16x8 bb = *(const bf16x8*)&Bs[(ct*16 + fr)*72 + kc*32 + hi*8];
        acc[0][ct] = __builtin_amdgcn_mfma_f32_16x16x32_bf16(a0, bb, acc[0][ct], 0,0,0);
        acc[1][ct] = __builtin_amdgcn_mfma_f32_16x16x32_bf16(a1, bb, acc[1][ct], 0,0,0);
      }
    }
  }

  __syncthreads();
  if (tid < 64){ s1[tid] = 0.f; s2[tid] = 0.f; }
  __syncthreads();
  int bidx = bm >> 11;
  #pragma unroll
  for (int ct=0; ct<4; ++ct){
    int o = bo + ct*16 + fr;
    float ga = g5[o];
    float s = 0.f, ss = 0.f, mx = -1e30f;
    #pragma unroll
    for (int g=0; g<2; ++g)
      #pragma unroll
      for (int reg=0; reg<4; ++reg){
        float v = acc[g][ct][reg];
        s += v; ss += v*v;
        float sel = ga >= 0.f ? v : -v;
        mx = fmaxf(mx, sel);
      }
    s  += __shfl_xor(s, 16);  s  += __shfl_xor(s, 32);
    ss += __shfl_xor(ss, 16); ss += __shfl_xor(ss, 32);
    mx = fmaxf(mx, __shfl_xor(mx, 16)); mx = fmaxf(mx, __shfl_xor(mx, 32));
    if (hi == 0){
      atomicAdd(&s1[ct*16 + fr], s);
      atomicAdd(&s2[ct*16 + fr], ss);
      atomicMax(&maxenc[bidx*512 + o], encf(mx));
    }
  }
  __syncthreads();
  if (tid < 64){
    atomicAdd(&sums[bo + tid],  s1[tid]);
    atomicAdd(&sumsq[bo + tid], s2[tid]);
  }
}

__global__ void zero_f_kernel(float* p, int n){
  int i = blockIdx.x*blockDim.x + threadIdx.x;
  if (i < n) p[i] = 0.f;
}
__global__ void zero_u_kernel(unsigned* p, int n){
  int i = blockIdx.x*blockDim.x + threadIdx.x;
  if (i < n) p[i] = 0u;
}

// ---------------- edge aggregation (fp32 P/Q/S) ----------------
__global__ __launch_bounds__(256) void edge_agg(const float* __restrict__ P, const float* __restrict__ Q,
      const int* __restrict__ idx, const float* __restrict__ gamma,
      float* __restrict__ S, float* __restrict__ sums, float* __restrict__ sumsq, int O){
  const int ROWS = 64;
  int rpi = 256 / O;
  int iters = ROWS / rpi;
  int row0 = blockIdx.x * ROWS;
  int tid = threadIdx.x;
  int o  = tid % O;
  int rl = tid / O;
  int b  = row0 / N_;
  __shared__ int sidx[4][KNN_K];
  __shared__ float s1[256], s2[256];
  float g = gamma[o];
  float csum=0.f, csumsq=0.f;
  for (int it=0; it<iters; ++it){
    __syncthreads();
    if (tid < KNN_K*rpi) sidx[tid/KNN_K][tid%KNN_K] = idx[(size_t)(row0 + it*rpi)*KNN_K + tid];
    __syncthreads();
    int row = row0 + it*rpi + rl;
    float q = Q[(size_t)row*O + o];
    float mx=-1e30f, mn=1e30f, s=0.f, ss=0.f;
    #pragma unroll
    for (int k=0;k<KNN_K;++k){
      int m = sidx[rl][k];
      float p = P[((size_t)b*N_ + m)*O + o];
      mx = fmaxf(mx,p); mn = fminf(mn,p);
      float y = p + q; s += y; ss += y*y;
    }
    csum += s; csumsq += ss;
    S[(size_t)row*O + o] = (g >= 0.f ? mx : mn) + q;
  }
  s1[tid]=0.f; s2[tid]=0.f;
  __syncthreads();
  atomicAdd(&s1[o], csum); atomicAdd(&s2[o], csumsq);
  __syncthreads();
  if (tid < O){ atomicAdd(&sums[tid], s1[tid]); atomicAdd(&sumsq[tid], s2[tid]); }
}

// ---------------- BN finalize ----------------
__global__ void bn_finalize(const float* __restrict__ sums, const float* __restrict__ sumsq,
                            const float* __restrict__ gamma, const float* __restrict__ beta,
                            float invM, float* __restrict__ scale, float* __restrict__ shift, int O){
  int o = blockIdx.x*blockDim.x + threadIdx.x;
  if (o >= O) return;
  float mu = sums[o]*invM;
  float var = sumsq[o]*invM - mu*mu;
  float rs = rsqrtf(var + EPS_);
  float sc = gamma[o]*rs;
  scale[o] = sc; shift[o] = beta[o] - mu*sc;
}

// ---------------- apply affine+lrelu, write into cat ----------------
__global__ void apply_write(const float* __restrict__ S, const float* __restrict__ scale,
                            const float* __restrict__ shift, float* __restrict__ cat, int off, int O){
  int i = blockIdx.x*blockDim.x + threadIdx.x;
  if (i >= B_*N_*O) return;
  int row = i / O, o = i - row*O;
  float v = S[i]*scale[o] + shift[o];
  cat[(size_t)row*512 + off + o] = lrelu(v);
}

// ---------------- pool ----------------
__global__ void pool_kernel(const unsigned* __restrict__ maxenc, const float* __restrict__ scale,
                            const float* __restrict__ shift, const float* __restrict__ g5,
                            float* __restrict__ pooled){
  int i = blockIdx.x*blockDim.x + threadIdx.x;
  if (i >= B_*512) return;
  int o = i & 511;
  float t = decf(maxenc[i]);
  float y = g5[o] >= 0.f ? t : -t;
  pooled[i] = lrelu(y*scale[o] + shift[o]);
}

// ---------------- final projection ----------------
__global__ void final_mm(const float* __restrict__ pooled, const float* __restrict__ we,
                         float* __restrict__ out){
  int i = blockIdx.x*blockDim.x + threadIdx.x;
  if (i >= B_*128) return;
  int b = i >> 7, j = i & 127;
  const float4* pp = (const float4*)(pooled + (size_t)b*512);
  const float4* wp = (const float4*)(we + (size_t)j*512);
  float s = 0.f;
  for (int c=0;c<128;++c){
    float4 a = pp[c], w = wp[c];
    s += a.x*w.x + a.y*w.y + a.z*w.z + a.w*w.w;
  }
  out[i] = s;
}

// ---------------- driver ----------------
struct Ws {
  float* cat; float* P; float* Q; float* S; int* idx; float* xx;
  float* sums; float* sumsq; float* scale; float* shift;
  unsigned* maxenc; float* pooled; short* fbf;
  float* pval; int* pidx;
};

template<int C, int CP>
static void run_layer(const Ws& W, const float* f, int lda, int O,
                      const float* w, const float* g, const float* bt,
                      int off_out, hipStream_t stream){
  const int M = B_*N_;
  size_t plane = (size_t)M*CP;
  convert_kernel<C, CP><<<M/4, 256, 0, stream>>>(f, lda, W.fbf, plane, W.xx);
  knn_mfma<CP><<<B_*(N_/64)*2, 256, 0, stream>>>(W.fbf, plane, W.xx, W.pval, W.pidx);
  knn_merge<<<(M+255)/256, 256, 0, stream>>>(W.pval, W.pidx, W.idx);
  int grid = (M/64)*(O/64);
  gemm_pq2<CP><<<grid, 256, 0, stream>>>(W.fbf, plane, w, C, W.P, W.Q, O);
  zero_f_kernel<<<4, 256, 0, stream>>>(W.sums, 1024);
  edge_agg<<<M/64, 256, 0, stream>>>(W.P, W.Q, W.idx, g, W.S, W.sums, W.sumsq, O);
  bn_finalize<<<(O+255)/256, 256, 0, stream>>>(W.sums, W.sumsq, g, bt,
                                               1.f/((float)M*KNN_K), W.scale, W.shift, O);
  apply_write<<<(M*O+255)/256, 256, 0, stream>>>(W.S, W.scale, W.shift, W.cat, off_out, O);
}

extern "C" void kernel_launch(void* const* d_in, const int* in_sizes, int n_in,
                              void* d_out, int out_size, void* d_ws, size_t ws_size,
                              hipStream_t stream) {
  const float* x  = (const float*)d_in[0];
  const float* w1 = (const float*)d_in[1];
  const float* g1 = (const float*)d_in[2];
  const float* b1 = (const float*)d_in[3];
  const float* w2 = (const float*)d_in[4];
  const float* g2 = (const float*)d_in[5];
  const float* b2 = (const float*)d_in[6];
  const float* w3 = (const float*)d_in[7];
  const float* g3 = (const float*)d_in[8];
  const float* b3 = (const float*)d_in[9];
  const float* w4 = (const float*)d_in[10];
  const float* g4 = (const float*)d_in[11];
  const float* b4 = (const float*)d_in[12];
  const float* w5 = (const float*)d_in[13];
  const float* g5 = (const float*)d_in[14];
  const float* b5 = (const float*)d_in[15];
  const float* we = (const float*)d_in[16];

  char* ws = (char*)d_ws;
  Ws W;
  size_t off = 0;
  W.cat   = (float*)(ws + off); off += (size_t)16*2048*512*4;
  W.P     = (float*)(ws + off); off += (size_t)16*2048*256*4;
  W.Q     = (float*)(ws + off); off += (size_t)16*2048*256*4;
  char* R = ws + off;            off += (size_t)16*2048*256*4;
  W.idx   = (int*)  (ws + off); off += (size_t)16*2048*20*4;
  W.xx    = (float*)(ws + off); off += (size_t)16*2048*4;
  W.sums  = (float*)(ws + off); off += 512*4;
  W.sumsq = (float*)(ws + off); off += 512*4;
  W.scale = (float*)(ws + off); off += 512*4;
  W.shift = (float*)(ws + off); off += 512*4;
  W.maxenc= (unsigned*)(ws + off); off += (size_t)16*512*4;
  W.pooled= (float*)(ws + off); off += (size_t)16*512*4;
  W.S     = (float*)R;              // S live [edge_agg, apply_write]
  W.fbf   = (short*)R;              // fbf live [convert, gemm_pq2] -- disjoint in time from S
  W.pval  = W.Q;                    // partials live [knn, merge]; Q written by gemm_pq2 after
  W.pidx  = (int*)(W.Q + (size_t)2*16*2048*KNN_K);

  const int M = B_*N_;

  run_layer<3,   32>(W, x,           3,   64,  w1, g1, b1, 0,   stream);
  run_layer<64,  64>(W, W.cat,       512, 64,  w2, g2, b2, 64,  stream);
  run_layer<64,  64>(W, W.cat + 64,  512, 128, w3, g3, b3, 128, stream);
  run_layer<128,128>(W, W.cat + 128, 512, 256, w4, g4, b4, 256, stream);

  // conv5 with fused BN-stats + signed-max epilogue (no y5 materialization)
  zero_f_kernel<<<4, 256, 0, stream>>>(W.sums, 1024);
  zero_u_kernel<<<32, 256, 0, stream>>>(W.maxenc, 16*512);
  gemm_bf16_stats<<<(M/128)*8, 256, 0, stream>>>(W.cat, w5, g5, W.sums, W.sumsq, W.maxenc);
  bn_finalize<<<2, 256, 0, stream>>>(W.sums, W.sumsq, g5, b5, 1.f/(float)M, W.scale, W.shift, 512);
  pool_kernel<<<(16*512+255)/256, 256, 0, stream>>>(W.maxenc, W.scale, W.shift, g5, W.pooled);
  final_mm<<<(16*128+255)/256, 256, 0, stream>>>(W.pooled, we, (float*)d_out);
}

// Round 17
// 1146.698 us; speedup vs baseline: 1.0686x; 1.0084x over previous
//
#include <hip/hip_runtime.h>
#include <hip/hip_bf16.h>
#include <cstdint>

#define B_ 16
#define N_ 2048
#define KNN_K 20
#define EPS_ 1e-5f
#define SLOPE_ 0.2f
#define IMS 4.8828125e-4f   // 1/2048

typedef __attribute__((ext_vector_type(4))) float f32x4;
typedef __attribute__((ext_vector_type(8))) short bf16x8;
typedef __attribute__((ext_vector_type(8))) _Float16 f16x8;

static __device__ __forceinline__ float lrelu(float v){ return v > 0.f ? v : SLOPE_*v; }

static __device__ __forceinline__ unsigned encf(float f){
  unsigned b = __float_as_uint(f);
  return (b & 0x80000000u) ? ~b : (b | 0x80000000u);
}
static __device__ __forceinline__ float decf(unsigned u){
  unsigned b = (u & 0x80000000u) ? (u ^ 0x80000000u) : ~u;
  return __uint_as_float(b);
}
static __device__ __forceinline__ short bfbits(float v){
  __hip_bfloat16 h = __float2bfloat16(v);
  return *reinterpret_cast<short*>(&h);
}
static __device__ __forceinline__ short h16(float v){
  _Float16 h = (_Float16)v;
  return *reinterpret_cast<short*>(&h);
}
static __device__ __forceinline__ float h2f(short s){
  _Float16 h = *reinterpret_cast<_Float16*>(&s);
  return (float)h;
}

// ---------------- convert: f -> 2 fp16 planes (h, (v-h)*2048) + xx (fp32) ----------------
template<int C, int CP>
__global__ __launch_bounds__(256) void convert_kernel(const float* __restrict__ f, int lda,
                                                      short* __restrict__ fbf, size_t plane,
                                                      float* __restrict__ xx){
  int wid  = (blockIdx.x * 256 + threadIdx.x) >> 6;   // one wave per row
  int lane = threadIdx.x & 63;
  if (wid >= B_*N_) return;
  const float* p = f + (size_t)wid*lda;
  float s = 0.f;
  for (int c = lane; c < CP; c += 64){
    float v = (c < C) ? p[c] : 0.f;
    short h = h16(v);
    short m = h16((v - h2f(h)) * 2048.f);
    size_t o = (size_t)wid*CP + c;
    fbf[o] = h;
    fbf[plane + o] = m;
    s += v*v;
  }
  #pragma unroll
  for (int off=32; off; off>>=1) s += __shfl_down(s, off);
  if (lane==0) xx[wid] = s;
}

// ---------------- fused MFMA distance (fp16 2-plane) + wave-coop top-20, m-split ----------------
// Register-lean variant: per-ct accumulators (8 regs), no prefetch regs (STAGE streams
// global->LDS overlapped with selection), xn dropped (row-uniform monotone shift).
// Stored value = 2*dot - xm. 2 barriers per tile; dtile in separate LDS region.
template<int CP>
__global__ __launch_bounds__(256, 3) void knn_mfma(const short* __restrict__ fbf, size_t plane,
                                                const float* __restrict__ xx,
                                                float* __restrict__ pval, int* __restrict__ pidx){
  constexpr int SP = CP + 8;          // shorts per LDS row
  constexpr int CH = CP/8;
  constexpr int KC = CP/32;
  constexpr int PFH = CP/32;          // 16B chunks per thread per plane
  __shared__ __align__(16) short fmb[2*64*SP];
  __shared__ float dtile[64*65];
  __shared__ float xm_s[64];

  int b   = blockIdx.x >> 6;
  int rem = blockIdx.x & 63;
  int n0  = (rem >> 1) << 6;
  int mh  = rem & 1;
  int mbase = mh << 10;
  int tid = threadIdx.x;
  int w    = tid >> 6;
  int lane = tid & 63;
  int fr = lane & 15, hi = lane >> 4;
  int r_loc = lane >> 2, csub = lane & 3;
  int gb = lane & 60;
  int myrow = w*16 + r_loc;
  size_t browoff = (size_t)b * N_;

  // fn A-fragments -- m-tile invariant, registers
  f16x8 aH[KC], aM[KC];
  {
    size_t arow = (browoff + n0 + w*16 + fr) * (size_t)CP;
    #pragma unroll
    for (int kc=0; kc<KC; ++kc){
      aH[kc] = *(const f16x8*)&fbf[arow + kc*32 + hi*8];
      aM[kc] = *(const f16x8*)&fbf[plane + arow + kc*32 + hi*8];
    }
  }

  float sv[5]; int si[5];
  #pragma unroll
  for (int j=0;j<5;++j){ sv[j] = -1e30f; si[j] = 0x7FFFFFFF; }

  // stream both planes global -> LDS (no prefetch registers)
  auto STAGE = [&](int mt){
    int m0 = mbase + (mt<<6);
    #pragma unroll
    for (int j=0;j<PFH;++j){
      int i = tid + j*256;
      int r = i/CH, cq = i - r*CH;
      size_t src = (browoff + m0 + r)*(size_t)CP + cq*8;
      *(f16x8*)&fmb[r*SP + cq*8] = *(const f16x8*)&fbf[src];
      *(f16x8*)&fmb[64*SP + r*SP + cq*8] = *(const f16x8*)&fbf[plane + src];
    }
    if (tid < 64) xm_s[tid] = xx[browoff + m0 + tid];
  };

  STAGE(0);
  __syncthreads();

  for (int mt = 0; mt < 16; ++mt){
    int m0 = mbase + (mt << 6);

    // per-ct MFMA (acc = 8 regs) + dtile write
    #pragma unroll
    for (int ct=0; ct<4; ++ct){
      f32x4 accH = (f32x4){0.f,0.f,0.f,0.f};
      f32x4 accM = accH;
      #pragma unroll
      for (int kc=0; kc<KC; ++kc){
        int boff = (ct*16 + fr)*SP + kc*32 + hi*8;
        f16x8 bh = *(const f16x8*)&fmb[boff];
        f16x8 bm = *(const f16x8*)&fmb[64*SP + boff];
        accH = __builtin_amdgcn_mfma_f32_16x16x32_f16(aH[kc], bh, accH, 0,0,0);
        accM = __builtin_amdgcn_mfma_f32_16x16x32_f16(aM[kc], bh, accM, 0,0,0);
        accM = __builtin_amdgcn_mfma_f32_16x16x32_f16(aH[kc], bm, accM, 0,0,0);
      }
      float xm = xm_s[ct*16 + fr];
      #pragma unroll
      for (int reg=0; reg<4; ++reg){
        int nl = w*16 + hi*4 + reg;
        dtile[nl*65 + ct*16 + fr] = 2.f*(accH[reg] + IMS*accM[reg]) - xm;
      }
    }
    __syncthreads();   // all fmb + xm_s reads done -> STAGE below may overwrite

    if (mt + 1 < 16) STAGE(mt + 1);   // loads land under the selection window

    // ---- wave-cooperative selection (r8-proven, bit-exact) ----
    int base = myrow*65 + csub*16;
    float thr = __shfl(sv[4], lane | 3);
    unsigned qm = 0u;
    #pragma unroll
    for (int jj=0; jj<16; ++jj){
      float v = dtile[base + jj];
      qm |= (v > thr) ? (1u << jj) : 0u;
    }
    unsigned long long bal = __ballot(qm != 0u);
    while (bal){
      unsigned nib = (unsigned)((bal >> gb) & 0xFull);
      int leader = nib ? (gb + (int)__builtin_ctz(nib)) : 64;
      int bbit = (int)__builtin_ctz(qm | 0x10000u);
      float mv = dtile[base + (bbit & 15)];
      int mid = m0 + (csub << 4) + bbit;
      float cv = __shfl(mv, leader);
      int   cid = __shfl(mid, leader);
      qm = (lane == leader) ? (qm & (qm - 1u)) : qm;
      int cnt = 0;
      #pragma unroll
      for (int j=0;j<5;++j) cnt += (sv[j] >= cv) ? 1 : 0;
      cnt += __shfl_xor(cnt, 1);
      cnt += __shfl_xor(cnt, 2);
      int pos = nib ? cnt : 20;
      float pv = __shfl_up(sv[4], 1);
      int   pi = __shfl_up(si[4], 1);
      #pragma unroll
      for (int j=0;j<5;++j){
        int g = csub*5 + j;
        float ns = (g < pos) ? sv[j] : ((g == pos) ? cv : pv);
        int   ni = (g < pos) ? si[j] : ((g == pos) ? cid : pi);
        pv = sv[j]; pi = si[j];
        sv[j] = ns; si[j] = ni;
      }
      bal = __ballot(qm != 0u);
    }

    if (mt + 1 < 16) __syncthreads();   // fmb(t+1) + xm_s ready
  }

  size_t orow = browoff + n0 + myrow;
  float* pvo = pval + (orow*2 + mh)*KNN_K + csub*5;
  int*   pio = pidx + (orow*2 + mh)*KNN_K + csub*5;
  #pragma unroll
  for (int j=0;j<5;++j){ pvo[j] = sv[j]; pio[j] = si[j]; }
}

// ---------------- merge two sorted-20 partial lists per row ----------------
__global__ __launch_bounds__(256) void knn_merge(const float* __restrict__ pval,
                                                 const int* __restrict__ pidx,
                                                 int* __restrict__ idxout){
  int r = blockIdx.x*256 + threadIdx.x;
  if (r >= B_*N_) return;
  const float* va = pval + (size_t)r*2*KNN_K;
  const float* vb = va + KNN_K;
  const int*   ia = pidx + (size_t)r*2*KNN_K;
  const int*   ib = ia + KNN_K;
  int i=0, j=0;
  #pragma unroll
  for (int t=0;t<KNN_K;++t){
    float a = va[i], bq = vb[j];
    bool ta = (a >= bq);   // tie -> half 0 (lower ids)
    idxout[(size_t)r*KNN_K + t] = ta ? ia[i] : ib[j];
    i += ta ? 1 : 0; j += ta ? 0 : 1;
  }
}

// ---------------- combined P+Q GEMM (fp16 2-plane): A staged once, wq = wB - wA inline ----------------
template<int CP>
__global__ __launch_bounds__(256) void gemm_pq2(const short* __restrict__ fbf, size_t plane,
                                                const float* __restrict__ Wsrc, int Cin,
                                                float* __restrict__ P, float* __restrict__ Qo, int O){
  constexpr int BK = (CP < 64) ? CP : 64;
  constexpr int SP = BK + 8;
  __shared__ short Ah[64*SP];
  __shared__ short Am[64*SP];
  __shared__ short WAh[64*SP];
  __shared__ short WAm[64*SP];
  __shared__ short WQh[64*SP];
  __shared__ short WQm[64*SP];
  int obl = O >> 6;
  int bo = ((int)blockIdx.x % obl) << 6;
  int bm = ((int)blockIdx.x / obl) << 6;
  int tid = threadIdx.x;
  int w = tid >> 6, lane = tid & 63;
  int fr = lane & 15, hi = lane >> 4;
  f32x4 aPH[4], aPM[4], aQH[4], aQM[4];
  #pragma unroll
  for (int ct=0; ct<4; ++ct){
    aPH[ct] = (f32x4){0.f,0.f,0.f,0.f};
    aPM[ct] = aPH[ct]; aQH[ct] = aPH[ct]; aQM[ct] = aPH[ct];
  }

  for (int k0=0; k0<CP; k0+=BK){
    __syncthreads();
    for (int i=tid; i < 64*(BK/8); i += 256){
      int r = i/(BK/8), cq = i%(BK/8);
      size_t src = ((size_t)bm + r)*CP + k0 + cq*8;
      *(f16x8*)&Ah[r*SP + cq*8] = *(const f16x8*)&fbf[src];
      *(f16x8*)&Am[r*SP + cq*8] = *(const f16x8*)&fbf[plane + src];
    }
    for (int i=tid; i < 64*(BK/8); i += 256){
      int r = i/(BK/8), cq = i%(BK/8);
      f16x8 vah, vam, vqh, vqm;
      #pragma unroll
      for (int e=0;e<8;++e){
        int c = k0 + cq*8 + e;
        float wa = 0.f, wqv = 0.f;
        if (c < Cin){
          wa  = Wsrc[(size_t)(bo + r)*2*Cin + c];
          wqv = Wsrc[(size_t)(bo + r)*2*Cin + Cin + c] - wa;
        }
        _Float16 ha = (_Float16)wa;
        vah[e] = ha;
        vam[e] = (_Float16)((wa - (float)ha) * 2048.f);
        _Float16 hq = (_Float16)wqv;
        vqh[e] = hq;
        vqm[e] = (_Float16)((wqv - (float)hq) * 2048.f);
      }
      *(f16x8*)&WAh[r*SP + cq*8] = vah;
      *(f16x8*)&WAm[r*SP + cq*8] = vam;
      *(f16x8*)&WQh[r*SP + cq*8] = vqh;
      *(f16x8*)&WQm[r*SP + cq*8] = vqm;
    }
    __syncthreads();
    #pragma unroll
    for (int kc=0; kc<BK/32; ++kc){
      f16x8 ah = *(const f16x8*)&Ah[(w*16 + fr)*SP + kc*32 + hi*8];
      f16x8 am = *(const f16x8*)&Am[(w*16 + fr)*SP + kc*32 + hi*8];
      #pragma unroll
      for (int ct=0; ct<4; ++ct){
        int boff = (ct*16 + fr)*SP + kc*32 + hi*8;
        f16x8 bh = *(const f16x8*)&WAh[boff];
        f16x8 bm = *(const f16x8*)&WAm[boff];
        f16x8 qh = *(const f16x8*)&WQh[boff];
        f16x8 qm = *(const f16x8*)&WQm[boff];
        aPH[ct] = __builtin_amdgcn_mfma_f32_16x16x32_f16(ah, bh, aPH[ct], 0,0,0);
        aPM[ct] = __builtin_amdgcn_mfma_f32_16x16x32_f16(am, bh, aPM[ct], 0,0,0);
        aPM[ct] = __builtin_amdgcn_mfma_f32_16x16x32_f16(ah, bm, aPM[ct], 0,0,0);
        aQH[ct] = __builtin_amdgcn_mfma_f32_16x16x32_f16(ah, qh, aQH[ct], 0,0,0);
        aQM[ct] = __builtin_amdgcn_mfma_f32_16x16x32_f16(am, qh, aQM[ct], 0,0,0);
        aQM[ct] = __builtin_amdgcn_mfma_f32_16x16x32_f16(ah, qm, aQM[ct], 0,0,0);
      }
    }
  }
  #pragma unroll
  for (int ct=0; ct<4; ++ct)
    #pragma unroll
    for (int reg=0; reg<4; ++reg){
      int row = bm + w*16 + hi*4 + reg;
      size_t o = (size_t)row*O + bo + ct*16 + fr;
      P[o]  = aPH[ct][reg] + IMS*aPM[ct][reg];
      Qo[o] = aQH[ct][reg] + IMS*aQM[ct][reg];
    }
}

// ---------------- conv5 GEMM (bf16 staged) with fused BN stats + signed max epilogue ----------------
__global__ __launch_bounds__(256) void gemm_bf16_stats(const float* __restrict__ A,
                                                       const float* __restrict__ Wt,
                                                       const float* __restrict__ g5,
                                                       float* __restrict__ sums,
                                                       float* __restrict__ sumsq,
                                                       unsigned* __restrict__ maxenc){
  __shared__ short As[128*72];
  __shared__ short Bs[64*72];
  __shared__ float s1[64], s2[64];
  int bm = (int)(blockIdx.x >> 3) << 7;
  int bo = (int)(blockIdx.x & 7) << 6;
  int tid = threadIdx.x;
  int w = tid >> 6, lane = tid & 63;
  int fr = lane & 15, hi = lane >> 4;
  f32x4 acc[2][4];
  #pragma unroll
  for (int g=0; g<2; ++g)
    #pragma unroll
    for (int ct=0; ct<4; ++ct) acc[g][ct] = (f32x4){0.f,0.f,0.f,0.f};

  for (int k0=0; k0<512; k0+=64){
    __syncthreads();
    #pragma unroll 2
    for (int i = tid; i < 1024; i += 256){
      int r = i >> 3, cq = i & 7;
      const float* src = &A[(size_t)(bm + r)*512 + k0 + cq*8];
      bf16x8 v;
      #pragma unroll
      for (int e=0;e<8;++e) v[e] = bfbits(src[e]);
      *(bf16x8*)&As[r*72 + cq*8] = v;
    }
    #pragma unroll 2
    for (int i = tid; i < 512; i += 256){
      int r = i >> 3, cq = i & 7;
      const float* src = &Wt[(size_t)(bo + r)*512 + k0 + cq*8];
      bf16x8 v;
      #pragma unroll
      for (int e=0;e<8;++e) v[e] = bfbits(src[e]);
      *(bf16x8*)&Bs[r*72 + cq*8] = v;
    }
    __syncthreads();
    #pragma unroll
    for (int kc=0; kc<2; ++kc){
      bf16x8 a0 = *(const bf16x8*)&As[(w*32 +      fr)*72 + kc*32 + hi*8];
      bf16x8 a1 = *(const bf16x8*)&As[(w*32 + 16 + fr)*72 + kc*32 + hi*8];
      #pragma unroll
      for (int ct=0; ct<4; ++ct){
        bf16x8 bb = *(const bf16x8*)&Bs[(ct*16 + fr)*72 + kc*32 + hi*8];
        acc[0][ct] = __builtin_amdgcn_mfma_f32_16x16x32_bf16(a0, bb, acc[0][ct], 0,0,0);
        acc[1][ct] = __builtin_amdgcn_mfma_f32_16x16x32_bf16(a1, bb, acc[1][ct], 0,0,0);
      }
    }
  }

  __syncthreads();
  if (tid < 64){ s1[tid] = 0.f; s2[tid] = 0.f; }
  __syncthreads();
  int bidx = bm >> 11;
  #pragma unroll
  for (int ct=0; ct<4; ++ct){
    int o = bo + ct*16 + fr;
    float ga = g5[o];
    float s = 0.f, ss = 0.f, mx = -1e30f;
    #pragma unroll
    for (int g=0; g<2; ++g)
      #pragma unroll
      for (int reg=0; reg<4; ++reg){
        float v = acc[g][ct][reg];
        s += v; ss += v*v;
        float sel = ga >= 0.f ? v : -v;
        mx = fmaxf(mx, sel);
      }
    s  += __shfl_xor(s, 16);  s  += __shfl_xor(s, 32);
    ss += __shfl_xor(ss, 16); ss += __shfl_xor(ss, 32);
    mx = fmaxf(mx, __shfl_xor(mx, 16)); mx = fmaxf(mx, __shfl_xor(mx, 32));
    if (hi == 0){
      atomicAdd(&s1[ct*16 + fr], s);
      atomicAdd(&s2[ct*16 + fr], ss);
      atomicMax(&maxenc[bidx*512 + o], encf(mx));
    }
  }
  __syncthreads();
  if (tid < 64){
    atomicAdd(&sums[bo + tid],  s1[tid]);
    atomicAdd(&sumsq[bo + tid], s2[tid]);
  }
}

__global__ void zero_f_kernel(float* p, int n){
  int i = blockIdx.x*blockDim.x + threadIdx.x;
  if (i < n) p[i] = 0.f;
}
__global__ void zero_u_kernel(unsigned* p, int n){
  int i = blockIdx.x*blockDim.x + threadIdx.x;
  if (i < n) p[i] = 0u;
}

// ---------------- edge aggregation (fp32 P/Q/S) ----------------
__global__ __launch_bounds__(256) void edge_agg(const float* __restrict__ P, const float* __restrict__ Q,
      const int* __restrict__ idx, const float* __restrict__ gamma,
      float* __restrict__ S, float* __restrict__ sums, float* __restrict__ sumsq, int O){
  const int ROWS = 64;
  int rpi = 256 / O;
  int iters = ROWS / rpi;
  int row0 = blockIdx.x * ROWS;
  int tid = threadIdx.x;
  int o  = tid % O;
  int rl = tid / O;
  int b  = row0 / N_;
  __shared__ int sidx[4][KNN_K];
  __shared__ float s1[256], s2[256];
  float g = gamma[o];
  float csum=0.f, csumsq=0.f;
  for (int it=0; it<iters; ++it){
    __syncthreads();
    if (tid < KNN_K*rpi) sidx[tid/KNN_K][tid%KNN_K] = idx[(size_t)(row0 + it*rpi)*KNN_K + tid];
    __syncthreads();
    int row = row0 + it*rpi + rl;
    float q = Q[(size_t)row*O + o];
    float mx=-1e30f, mn=1e30f, s=0.f, ss=0.f;
    #pragma unroll
    for (int k=0;k<KNN_K;++k){
      int m = sidx[rl][k];
      float p = P[((size_t)b*N_ + m)*O + o];
      mx = fmaxf(mx,p); mn = fminf(mn,p);
      float y = p + q; s += y; ss += y*y;
    }
    csum += s; csumsq += ss;
    S[(size_t)row*O + o] = (g >= 0.f ? mx : mn) + q;
  }
  s1[tid]=0.f; s2[tid]=0.f;
  __syncthreads();
  atomicAdd(&s1[o], csum); atomicAdd(&s2[o], csumsq);
  __syncthreads();
  if (tid < O){ atomicAdd(&sums[tid], s1[tid]); atomicAdd(&sumsq[tid], s2[tid]); }
}

// ---------------- BN finalize ----------------
__global__ void bn_finalize(const float* __restrict__ sums, const float* __restrict__ sumsq,
                            const float* __restrict__ gamma, const float* __restrict__ beta,
                            float invM, float* __restrict__ scale, float* __restrict__ shift, int O){
  int o = blockIdx.x*blockDim.x + threadIdx.x;
  if (o >= O) return;
  float mu = sums[o]*invM;
  float var = sumsq[o]*invM - mu*mu;
  float rs = rsqrtf(var + EPS_);
  float sc = gamma[o]*rs;
  scale[o] = sc; shift[o] = beta[o] - mu*sc;
}

// ---------------- apply affine+lrelu, write into cat ----------------
__global__ void apply_write(const float* __restrict__ S, const float* __restrict__ scale,
                            const float* __restrict__ shift, float* __restrict__ cat, int off, int O){
  int i = blockIdx.x*blockDim.x + threadIdx.x;
  if (i >= B_*N_*O) return;
  int row = i / O, o = i - row*O;
  float v = S[i]*scale[o] + shift[o];
  cat[(size_t)row*512 + off + o] = lrelu(v);
}

// ---------------- pool ----------------
__global__ void pool_kernel(const unsigned* __restrict__ maxenc, const float* __restrict__ scale,
                            const float* __restrict__ shift, const float* __restrict__ g5,
                            float* __restrict__ pooled){
  int i = blockIdx.x*blockDim.x + threadIdx.x;
  if (i >= B_*512) return;
  int o = i & 511;
  float t = decf(maxenc[i]);
  float y = g5[o] >= 0.f ? t : -t;
  pooled[i] = lrelu(y*scale[o] + shift[o]);
}

// ---------------- final projection ----------------
__global__ void final_mm(const float* __restrict__ pooled, const float* __restrict__ we,
                         float* __restrict__ out){
  int i = blockIdx.x*blockDim.x + threadIdx.x;
  if (i >= B_*128) return;
  int b = i >> 7, j = i & 127;
  const float4* pp = (const float4*)(pooled + (size_t)b*512);
  const float4* wp = (const float4*)(we + (size_t)j*512);
  float s = 0.f;
  for (int c=0;c<128;++c){
    float4 a = pp[c], w = wp[c];
    s += a.x*w.x + a.y*w.y + a.z*w.z + a.w*w.w;
  }
  out[i] = s;
}

// ---------------- driver ----------------
struct Ws {
  float* cat; float* P; float* Q; float* S; int* idx; float* xx;
  float* sums; float* sumsq; float* scale; float* shift;
  unsigned* maxenc; float* pooled; short* fbf;
  float* pval; int* pidx;
};

template<int C, int CP>
static void run_layer(const Ws& W, const float* f, int lda, int O,
                      const float* w, const float* g, const float* bt,
                      int off_out, hipStream_t stream){
  const int M = B_*N_;
  size_t plane = (size_t)M*CP;
  convert_kernel<C, CP><<<M/4, 256, 0, stream>>>(f, lda, W.fbf, plane, W.xx);
  knn_mfma<CP><<<B_*(N_/64)*2, 256, 0, stream>>>(W.fbf, plane, W.xx, W.pval, W.pidx);
  knn_merge<<<(M+255)/256, 256, 0, stream>>>(W.pval, W.pidx, W.idx);
  int grid = (M/64)*(O/64);
  gemm_pq2<CP><<<grid, 256, 0, stream>>>(W.fbf, plane, w, C, W.P, W.Q, O);
  zero_f_kernel<<<4, 256, 0, stream>>>(W.sums, 1024);
  edge_agg<<<M/64, 256, 0, stream>>>(W.P, W.Q, W.idx, g, W.S, W.sums, W.sumsq, O);
  bn_finalize<<<(O+255)/256, 256, 0, stream>>>(W.sums, W.sumsq, g, bt,
                                               1.f/((float)M*KNN_K), W.scale, W.shift, O);
  apply_write<<<(M*O+255)/256, 256, 0, stream>>>(W.S, W.scale, W.shift, W.cat, off_out, O);
}

extern "C" void kernel_launch(void* const* d_in, const int* in_sizes, int n_in,
                              void* d_out, int out_size, void* d_ws, size_t ws_size,
                              hipStream_t stream) {
  const float* x  = (const float*)d_in[0];
  const float* w1 = (const float*)d_in[1];
  const float* g1 = (const float*)d_in[2];
  const float* b1 = (const float*)d_in[3];
  const float* w2 = (const float*)d_in[4];
  const float* g2 = (const float*)d_in[5];
  const float* b2 = (const float*)d_in[6];
  const float* w3 = (const float*)d_in[7];
  const float* g3 = (const float*)d_in[8];
  const float* b3 = (const float*)d_in[9];
  const float* w4 = (const float*)d_in[10];
  const float* g4 = (const float*)d_in[11];
  const float* b4 = (const float*)d_in[12];
  const float* w5 = (const float*)d_in[13];
  const float* g5 = (const float*)d_in[14];
  const float* b5 = (const float*)d_in[15];
  const float* we = (const float*)d_in[16];

  char* ws = (char*)d_ws;
  Ws W;
  size_t off = 0;
  W.cat   = (float*)(ws + off); off += (size_t)16*2048*512*4;
  W.P     = (float*)(ws + off); off += (size_t)16*2048*256*4;
  W.Q     = (float*)(ws + off); off += (size_t)16*2048*256*4;
  char* R = ws + off;            off += (size_t)16*2048*256*4;
  W.idx   = (int*)  (ws + off); off += (size_t)16*2048*20*4;
  W.xx    = (float*)(ws + off); off += (size_t)16*2048*4;
  W.sums  = (float*)(ws + off); off += 512*4;
  W.sumsq = (float*)(ws + off); off += 512*4;
  W.scale = (float*)(ws + off); off += 512*4;
  W.shift = (float*)(ws + off); off += 512*4;
  W.maxenc= (unsigned*)(ws + off); off += (size_t)16*512*4;
  W.pooled= (float*)(ws + off); off += (size_t)16*512*4;
  W.S     = (float*)R;              // S live [edge_agg, apply_write]
  W.fbf   = (short*)R;              // fbf live [convert, gemm_pq2] -- disjoint in time from S
  W.pval  = W.Q;                    // partials live [knn, merge]; Q written by gemm_pq2 after
  W.pidx  = (int*)(W.Q + (size_t)2*16*2048*KNN_K);

  const int M = B_*N_;

  run_layer<3,   32>(W, x,           3,   64,  w1, g1, b1, 0,   stream);
  run_layer<64,  64>(W, W.cat,       512, 64,  w2, g2, b2, 64,  stream);
  run_layer<64,  64>(W, W.cat + 64,  512, 128, w3, g3, b3, 128, stream);
  run_layer<128,128>(W, W.cat + 128, 512, 256, w4, g4, b4, 256, stream);

  // conv5 with fused BN-stats + signed-max epilogue (no y5 materialization)
  zero_f_kernel<<<4, 256, 0, stream>>>(W.sums, 1024);
  zero_u_kernel<<<32, 256, 0, stream>>>(W.maxenc, 16*512);
  gemm_bf16_stats<<<(M/128)*8, 256, 0, stream>>>(W.cat, w5, g5, W.sums, W.sumsq, W.maxenc);
  bn_finalize<<<2, 256, 0, stream>>>(W.sums, W.sumsq, g5, b5, 1.f/(float)M, W.scale, W.shift, 512);
  pool_kernel<<<(16*512+255)/256, 256, 0, stream>>>(W.maxenc, W.scale, W.shift, g5, W.pooled);
  final_mm<<<(16*128+255)/256, 256, 0, stream>>>(W.pooled, we, (float*)d_out);
}